// Round 8
// baseline (787.002 us; speedup 1.0000x reference)
//
#include <hip/hip_runtime.h>
#include <hip/hip_bf16.h>
#include <stdint.h>

// Problem constants
#define B_    16
#define C_    512
#define HIMG  56
#define N_    3136
#define NK_   49
#define NH_   8
#define HD_   64
#define JP_   52          // padded NK (49 -> 52) so 8*52 = 416 = 13*32
#define J_    416
#define HID_  24
#define POS_  153664      // N_ * NK_
#define PLH_  9834496     // u16 elems per attn head-plane: B_*N_*NK_*4
#define CNT_  1229312.0f  // 8 * 3136 * 49 (elements per group-norm group)
#define EPS_  1e-5f
#define SCALE_ 0.125f     // HEAD_DIM^-0.5

typedef __attribute__((ext_vector_type(8))) short short8;
typedef __attribute__((ext_vector_type(4))) float floatx4;

static __device__ __forceinline__ uint16_t f2bf(float f) {
  uint32_t u = __builtin_bit_cast(uint32_t, f);
  u = (u + 0x7FFFu + ((u >> 16) & 1u)) >> 16;
  return (uint16_t)u;
}
static __device__ __forceinline__ float bf2f(uint16_t h) {
  uint32_t u = ((uint32_t)h) << 16;
  return __builtin_bit_cast(float, u);
}
static __device__ __forceinline__ uint16_t f2h(float f) {
  _Float16 h = (_Float16)f;
  return __builtin_bit_cast(uint16_t, h);
}
static __device__ __forceinline__ float h2f(uint16_t u) {
  return (float)__builtin_bit_cast(_Float16, u);
}
static __device__ __forceinline__ float swishf(float z) {
  return z * __builtin_amdgcn_rcpf(1.f + __expf(-z));
}
// load 8 fp16 attn values for (b,n,m): 4 from each head-plane
static __device__ __forceinline__ void ld_attn8(const uint16_t* __restrict__ attn,
                                                size_t off, float* a) {
  uint2 v0 = *(const uint2*)(attn + off);
  uint2 v1 = *(const uint2*)(attn + PLH_ + off);
  a[0] = h2f((uint16_t)(v0.x & 0xFFFFu)); a[1] = h2f((uint16_t)(v0.x >> 16));
  a[2] = h2f((uint16_t)(v0.y & 0xFFFFu)); a[3] = h2f((uint16_t)(v0.y >> 16));
  a[4] = h2f((uint16_t)(v1.x & 0xFFFFu)); a[5] = h2f((uint16_t)(v1.x >> 16));
  a[6] = h2f((uint16_t)(v1.y & 0xFFFFu)); a[7] = h2f((uint16_t)(v1.y >> 16));
}

// gn1 affine (al,be) for group g's 8 channels from per-batch moments
static __device__ __forceinline__ void gn1_affine(const float* __restrict__ moms,
    const float* __restrict__ ew, const float* __restrict__ gs,
    const float* __restrict__ gb, int b, int g, float* al, float* be) {
  float m1[8];
#pragma unroll
  for (int h = 0; h < 8; ++h) m1[h] = moms[b * 44 + h];
  float sum = 0.f, ssq = 0.f;
#pragma unroll
  for (int o2 = 0; o2 < 8; ++o2) {
    int o = g * 8 + o2;
    float e[8];
#pragma unroll
    for (int h = 0; h < 8; ++h) e[h] = ew[o * 8 + h];
    float so = 0.f;
#pragma unroll
    for (int h = 0; h < 8; ++h) so += e[h] * m1[h];
    sum += so;
    int idx = 8;
#pragma unroll
    for (int h = 0; h < 8; ++h)
#pragma unroll
      for (int h2 = h; h2 < 8; ++h2) {
        float cf = e[h] * e[h2] * ((h == h2) ? 1.f : 2.f);
        ssq += cf * moms[b * 44 + idx];
        ++idx;
      }
  }
  float mean = sum * (1.f / CNT_);
  float var = ssq * (1.f / CNT_) - mean * mean;
  float inv = rsqrtf(var + EPS_);
#pragma unroll
  for (int o2 = 0; o2 < 8; ++o2) {
    al[o2] = inv * gs[g * 8 + o2];
    be[o2] = gb[g * 8 + o2] - mean * al[o2];
  }
}

// ---------------------------------------------------------------------------
// 1) kvxbf[b][m][c] (bf16) = depthwise 8x8/stride-8 downsample; also xbf
// ---------------------------------------------------------------------------
__global__ __launch_bounds__(256) void k_kvx(const float* __restrict__ x,
                                             const float* __restrict__ dw,
                                             uint16_t* __restrict__ kvxbf,
                                             uint16_t* __restrict__ xbf) {
  int g = blockIdx.x * 256 + threadIdx.x;
  int b = g / (C_ * NK_);
  int rem = g % (C_ * NK_);
  int c = rem / NK_;
  int m = rem % NK_;
  int ph = m / 7, pw = m % 7;
  const size_t base = ((size_t)(b * C_ + c)) * N_ + (ph * 8) * HIMG + pw * 8;
  const float* xp = x + base;
  uint16_t* xbp = xbf + base;
  const float* wp = dw + c * 64;
  float acc = 0.f;
#pragma unroll
  for (int i = 0; i < 8; ++i) {
    float4 a  = *(const float4*)(xp + i * HIMG);
    float4 bq = *(const float4*)(xp + i * HIMG + 4);
    acc += a.x*wp[i*8+0] + a.y*wp[i*8+1] + a.z*wp[i*8+2] + a.w*wp[i*8+3]
         + bq.x*wp[i*8+4] + bq.y*wp[i*8+5] + bq.z*wp[i*8+6] + bq.w*wp[i*8+7];
    uint32_t q0 = (uint32_t)f2bf(a.x)  | ((uint32_t)f2bf(a.y)  << 16);
    uint32_t q1 = (uint32_t)f2bf(a.z)  | ((uint32_t)f2bf(a.w)  << 16);
    uint32_t q2 = (uint32_t)f2bf(bq.x) | ((uint32_t)f2bf(bq.y) << 16);
    uint32_t q3 = (uint32_t)f2bf(bq.z) | ((uint32_t)f2bf(bq.w) << 16);
    *(uint4*)(xbp + (size_t)i * HIMG) = make_uint4(q0, q1, q2, q3);
  }
  kvxbf[((size_t)(b * NK_ + m)) * C_ + c] = f2bf(acc);
}

// ---------------------------------------------------------------------------
// 2) kv[b][m][col] = sum_c kvx[b][m][c] * kv_w[c][col]  -- MFMA bf16
// ---------------------------------------------------------------------------
__global__ __launch_bounds__(256) void k_kv(const uint16_t* __restrict__ kvxbf,
                                            const float* __restrict__ kv_w,
                                            float* __restrict__ kv) {
  const int ct = blockIdx.x, b = blockIdx.y;
  const int j0 = ct * 64;
  const int tid = threadIdx.x, wvid = tid >> 6, lane = tid & 63;
  __shared__ __align__(16) uint32_t A32[64 * 20];
  __shared__ __align__(16) uint32_t B32[64 * 20];
  floatx4 acc[4];
#pragma unroll
  for (int t = 0; t < 4; ++t) acc[t] = (floatx4){0.f,0.f,0.f,0.f};
  const int am = tid & 63, ak = tid >> 6;
  const int bj = tid & 63, bk = tid >> 6;
  for (int ks = 0; ks < 16; ++ks) {
    const int c0 = ks * 32;
    __syncthreads();
    {
      uint4 av = make_uint4(0, 0, 0, 0);
      if (am < NK_)
        av = *(const uint4*)(kvxbf + ((size_t)(b * NK_ + am)) * C_ + c0 + ak * 8);
      *(uint4*)&A32[am * 20 + ak * 4] = av;
    }
    {
      uint32_t pk[4];
#pragma unroll
      for (int r = 0; r < 4; ++r) {
        float f0 = kv_w[(size_t)(c0 + bk * 8 + 2 * r)     * 1024 + j0 + bj];
        float f1 = kv_w[(size_t)(c0 + bk * 8 + 2 * r + 1) * 1024 + j0 + bj];
        pk[r] = (uint32_t)f2bf(f0) | ((uint32_t)f2bf(f1) << 16);
      }
      *(uint4*)&B32[bj * 20 + bk * 4] = make_uint4(pk[0], pk[1], pk[2], pk[3]);
    }
    __syncthreads();
    short8 af = *(const short8*)&A32[(wvid * 16 + (lane & 15)) * 20 + (lane >> 4) * 4];
#pragma unroll
    for (int t = 0; t < 4; ++t) {
      short8 bfb = *(const short8*)&B32[(t * 16 + (lane & 15)) * 20 + (lane >> 4) * 4];
      acc[t] = __builtin_amdgcn_mfma_f32_16x16x32_bf16(af, bfb, acc[t], 0, 0, 0);
    }
  }
  const int rb = wvid * 16 + ((lane >> 4) << 2), cb = lane & 15;
#pragma unroll
  for (int t = 0; t < 4; ++t)
#pragma unroll
    for (int r2 = 0; r2 < 4; ++r2) {
      int m = rb + r2;
      if (m < NK_)
        kv[((size_t)(b * NK_ + m)) * 1024 + j0 + t * 16 + cb] = acc[t][r2];
    }
}

// ---------------------------------------------------------------------------
// 3+4 merged) z=0: wqkT[b][h*52+m][c] = SCALE*sum_d q_w[c][h*64+d]*k[b][h][m][d]
//             z=1: wvT[b][c'][h*52+m] = sum_d v[b][h][m][d]*proj_w[h*64+d][c']
// ---------------------------------------------------------------------------
__global__ __launch_bounds__(256) void k_wqkv(const float* __restrict__ kv,
                                              const float* __restrict__ q_w,
                                              const float* __restrict__ proj_w,
                                              uint16_t* __restrict__ wqkT,
                                              uint16_t* __restrict__ wvT) {
  int b = blockIdx.x, h = blockIdx.y;
  __shared__ float sm[56 * 64];
  if (blockIdx.z == 0) {
    for (int idx = threadIdx.x; idx < 56 * 64; idx += 256) {
      int m = idx >> 6, d = idx & 63;
      sm[idx] = (m < NK_) ? kv[((size_t)(b * NK_ + m)) * 1024 + h * HD_ + d] : 0.f;
    }
    __syncthreads();
#pragma unroll
    for (int cc = 0; cc < 2; ++cc) {
      int c = threadIdx.x + cc * 256;
      float qrow[64];
      const float* qp = q_w + (size_t)c * C_ + h * HD_;
#pragma unroll
      for (int d = 0; d < 64; ++d) qrow[d] = qp[d];
      for (int mc = 0; mc < NK_; mc += 8) {
        int cnt = min(8, NK_ - mc);
        float acc[8] = {0,0,0,0,0,0,0,0};
        for (int d = 0; d < 64; ++d) {
          float q = qrow[d];
#pragma unroll
          for (int i = 0; i < 8; ++i) acc[i] += q * sm[(mc + i) * 64 + d];
        }
        for (int i = 0; i < cnt; ++i)
          wqkT[((size_t)(b * J_ + h * JP_ + mc + i)) * C_ + c] = f2bf(acc[i] * SCALE_);
      }
    }
    for (int idx = threadIdx.x; idx < 3 * C_; idx += 256) {
      int rr = idx / C_, c = idx % C_;
      wqkT[((size_t)(b * J_ + h * JP_ + 49 + rr)) * C_ + c] = 0;
    }
  } else {
    for (int idx = threadIdx.x; idx < 56 * 64; idx += 256) {
      int m = idx >> 6, d = idx & 63;
      sm[idx] = (m < NK_) ? kv[((size_t)(b * NK_ + m)) * 1024 + 512 + h * HD_ + d] : 0.f;
    }
    __syncthreads();
#pragma unroll
    for (int cc = 0; cc < 2; ++cc) {
      int c = threadIdx.x + cc * 256;
      for (int mc = 0; mc < NK_; mc += 8) {
        int cnt = min(8, NK_ - mc);
        float acc[8] = {0,0,0,0,0,0,0,0};
        for (int d = 0; d < 64; ++d) {
          float w = proj_w[(size_t)(h * HD_ + d) * C_ + c];
#pragma unroll
          for (int i = 0; i < 8; ++i) acc[i] += sm[(mc + i) * 64 + d] * w;
        }
        uint16_t* dst = wvT + ((size_t)(b * C_ + c)) * J_ + h * JP_ + mc;
        if (cnt == 8) {
          uint32_t pk[4];
#pragma unroll
          for (int i = 0; i < 4; ++i)
            pk[i] = (uint32_t)f2bf(acc[2*i]) | ((uint32_t)f2bf(acc[2*i+1]) << 16);
          *(uint2*)(dst)     = make_uint2(pk[0], pk[1]);
          *(uint2*)(dst + 4) = make_uint2(pk[2], pk[3]);
        } else {
          for (int i = 0; i < cnt; ++i) dst[i] = f2bf(acc[i]);
        }
      }
      uint16_t* pd = wvT + ((size_t)(b * C_ + c)) * J_ + h * JP_ + 49;
      pd[0] = 0; pd[1] = 0; pd[2] = 0;
    }
  }
}

// ---------------------------------------------------------------------------
// 5) GEMM1 + softmax, ALL 8 heads per block: A (xbf tile) staged & read ONCE,
//    26 MFMA tiles, 2x unrolled epilogue -> plane 0 (heads 0-3), plane 1 (4-7).
// ---------------------------------------------------------------------------
__global__ __launch_bounds__(256) void k_attn(const uint16_t* __restrict__ xbf,
                                              const uint16_t* __restrict__ wqkT,
                                              const float* __restrict__ rel_bias,
                                              uint16_t* __restrict__ attn) {
  const int mt = blockIdx.x, b = blockIdx.y;
  const int n0 = mt * 64;
  const int tid = threadIdx.x, wvid = tid >> 6, lane = tid & 63;
  // LDS: A32 [64][20] @0 (5120); B32 [416][20] @5120 (33280) -> staging 38400
  //      Ss [64][212] f32 aliases [0, 54272) in the epilogue
  __shared__ __align__(16) char smem[64 * 212 * 4];
  uint32_t* A32 = (uint32_t*)smem;
  uint32_t* B32 = (uint32_t*)(smem + 5120);
  float* Ss = (float*)smem;

  floatx4 acc[26];
#pragma unroll
  for (int t = 0; t < 26; ++t) acc[t] = (floatx4){0.f,0.f,0.f,0.f};

  const int an = tid & 63, acp = tid >> 6;
  for (int ks = 0; ks < 16; ++ks) {
    const int c0 = ks * 32;
    __syncthreads();
    {
      const uint16_t* xb = xbf + ((size_t)(b * C_ + c0 + acp * 8)) * N_ + n0 + an;
      uint32_t pk[4];
#pragma unroll
      for (int jj = 0; jj < 4; ++jj) {
        uint32_t f0 = xb[(size_t)(2*jj) * N_];
        uint32_t f1 = xb[(size_t)(2*jj+1) * N_];
        pk[jj] = f0 | (f1 << 16);
      }
      *(uint4*)&A32[an * 20 + acp * 4] = make_uint4(pk[0], pk[1], pk[2], pk[3]);
    }
    for (int idx = tid; idx < 1664; idx += 256) {
      int jl = idx >> 2, q = idx & 3;
      uint4 v = *(const uint4*)(wqkT + ((size_t)b * J_ + jl) * C_ + c0 + q * 8);
      *(uint4*)&B32[jl * 20 + q * 4] = v;
    }
    __syncthreads();
    short8 af = *(const short8*)&A32[(wvid * 16 + (lane & 15)) * 20 + (lane >> 4) * 4];
#pragma unroll
    for (int t = 0; t < 26; ++t) {
      short8 bfb = *(const short8*)&B32[(16 * t + (lane & 15)) * 20 + (lane >> 4) * 4];
      acc[t] = __builtin_amdgcn_mfma_f32_16x16x32_bf16(af, bfb, acc[t], 0, 0, 0);
    }
  }
  // epilogue: two halves (heads 0-3 -> plane 0, heads 4-7 -> plane 1)
#pragma unroll
  for (int half = 0; half < 2; ++half) {
    __syncthreads();   // prior-phase Ss/staging reads complete
    {
      const int rb = wvid * 16 + ((lane >> 4) << 2), cb = lane & 15;
#pragma unroll
      for (int t = 0; t < 13; ++t)
#pragma unroll
        for (int r2 = 0; r2 < 4; ++r2)
          Ss[(rb + r2) * 212 + t * 16 + cb] = acc[half * 13 + t][r2];
    }
    __syncthreads();
    {
      const int row = tid >> 2, hh = tid & 3;
      const int n = n0 + row;
      const float* bias = rel_bias + (size_t)n * NK_;
      float* srow = &Ss[row * 212 + hh * JP_];
      float mx = -1e30f;
      for (int m = 0; m < NK_; ++m) mx = fmaxf(mx, srow[m] + bias[m]);
      float sum = 0.f;
      for (int m = 0; m < NK_; ++m) { float e = __expf(srow[m] + bias[m] - mx); srow[m] = e; sum += e; }
      float inv = 1.f / sum;
      for (int m = 0; m < NK_; ++m) srow[m] *= inv;
    }
    __syncthreads();
    uint16_t* dst = attn + (size_t)half * PLH_ + ((size_t)b * N_ + n0) * NK_ * 4;
    for (int task = tid; task < 64 * NK_; task += 256) {
      int row = task / NK_, m = task % NK_;
      const float* sr = &Ss[row * 212];
      uint32_t lo = (uint32_t)f2h(sr[m])         | ((uint32_t)f2h(sr[JP_ + m])   << 16);
      uint32_t hi = (uint32_t)f2h(sr[2*JP_ + m]) | ((uint32_t)f2h(sr[3*JP_ + m]) << 16);
      *(uint2*)(dst + (size_t)task * 4) = make_uint2(lo, hi);
    }
  }
}

// ---------------------------------------------------------------------------
// 6) attn moments per batch (fp16 attn, two planes)
// ---------------------------------------------------------------------------
__global__ __launch_bounds__(256) void k_moms(const uint16_t* __restrict__ attn,
                                              float* __restrict__ moms) {
  int nt = blockIdx.x, b = blockIdx.y;
  float vals[44];
#pragma unroll
  for (int k = 0; k < 44; ++k) vals[k] = 0.f;
  for (int task = threadIdx.x; task < 64 * NK_; task += 256) {
    float a[8];
    ld_attn8(attn, ((size_t)b * N_ + nt * 64) * NK_ * 4 + (size_t)task * 4, a);
#pragma unroll
    for (int h = 0; h < 8; ++h) vals[h] += a[h];
    int idx = 8;
#pragma unroll
    for (int h = 0; h < 8; ++h)
#pragma unroll
      for (int h2 = h; h2 < 8; ++h2) { vals[idx] += a[h] * a[h2]; ++idx; }
  }
  __shared__ float red[4][44];
  int lane = threadIdx.x & 63, wvid = threadIdx.x >> 6;
#pragma unroll
  for (int k = 0; k < 44; ++k) {
#pragma unroll
    for (int off = 32; off; off >>= 1) vals[k] += __shfl_down(vals[k], off, 64);
  }
  if (lane == 0) {
#pragma unroll
    for (int k = 0; k < 44; ++k) red[wvid][k] = vals[k];
  }
  __syncthreads();
  if (threadIdx.x < 44) {
    float t = red[0][threadIdx.x] + red[1][threadIdx.x] + red[2][threadIdx.x] + red[3][threadIdx.x];
    atomicAdd(&moms[b * 44 + threadIdx.x], t);
  }
}

// ---------------------------------------------------------------------------
// 6b) gn1 affine precompute
// ---------------------------------------------------------------------------
__global__ void k_aff(const float* __restrict__ moms, const float* __restrict__ ew,
                      const float* __restrict__ gn1_s, const float* __restrict__ gn1_b,
                      float* __restrict__ gn1ab) {
  int t = threadIdx.x;
  if (t >= 48) return;
  int b = t / 3, g = t % 3;
  float al[8], be[8];
  gn1_affine(moms, ew, gn1_s, gn1_b, b, g, al, be);
#pragma unroll
  for (int o = 0; o < 8; ++o) { gn1ab[t * 16 + o] = al[o]; gn1ab[t * 16 + 8 + o] = be[o]; }
}

// ---------------------------------------------------------------------------
// 6c) gn2 affine precompute (after k_dla0)
// ---------------------------------------------------------------------------
__global__ void k_aff2(const float* __restrict__ gn2sums, const float* __restrict__ gn2_s,
                       const float* __restrict__ gn2_b, float* __restrict__ gn2ab) {
  int t = threadIdx.x;
  if (t >= 48) return;
  int b = t / 3, g = t % 3;
  float s2 = gn2sums[b * 6 + g * 2], q2 = gn2sums[b * 6 + g * 2 + 1];
  float mean = s2 * (1.f / CNT_);
  float var = q2 * (1.f / CNT_) - mean * mean;
  float inv = rsqrtf(var + EPS_);
#pragma unroll
  for (int o = 0; o < 8; ++o) {
    float al = inv * gn2_s[g * 8 + o];
    gn2ab[t * 16 + o] = al;
    gn2ab[t * 16 + 8 + o] = gn2_b[g * 8 + o] - mean * al;
  }
}

// ---------------------------------------------------------------------------
// 7a) DLA pass 0: h1 -> LDS, 3x3 stencil -> a2; gn2 sums; opt. store a2 fp16
// ---------------------------------------------------------------------------
template<bool STORE>
__global__ __launch_bounds__(256) void k_dla0_t(const uint16_t* __restrict__ attn,
    const float* __restrict__ ew, const float* __restrict__ gn1ab,
    const float* __restrict__ dww, float* __restrict__ gn2sums,
    uint16_t* __restrict__ a2buf) {
  const int nt = blockIdx.x, b = blockIdx.y, g = blockIdx.z;  // 196 x 16 x 3
  const int n0 = nt * 16;
  __shared__ __align__(16) float h1s[18 * 51 * 8];   // 29376 B
  __shared__ float red[4][2];
  float al[8], be[8];
  {
    const float* ab = gn1ab + (b * 3 + g) * 16;
#pragma unroll
    for (int o = 0; o < 8; ++o) { al[o] = ab[o]; be[o] = ab[8 + o]; }
  }
  for (int task = threadIdx.x; task < 18 * NK_; task += 256) {
    int r = task / NK_, m = task % NK_;
    int n = n0 - 1 + r;
    float h1v[8];
    if (n < 0 || n >= N_) {
#pragma unroll
      for (int o = 0; o < 8; ++o) h1v[o] = 0.f;
    } else {
      float a[8];
      ld_attn8(attn, (((size_t)b * N_ + n) * NK_ + m) * 4, a);
#pragma unroll
      for (int o = 0; o < 8; ++o) {
        float v = 0.f;
#pragma unroll
        for (int h = 0; h < 8; ++h) v += ew[(g * 8 + o) * 8 + h] * a[h];
        h1v[o] = swishf(v * al[o] + be[o]);
      }
    }
    float* dst = &h1s[(r * 51 + m + 1) * 8];
    *(float4*)dst = make_float4(h1v[0], h1v[1], h1v[2], h1v[3]);
    *(float4*)(dst + 4) = make_float4(h1v[4], h1v[5], h1v[6], h1v[7]);
  }
  for (int idx = threadIdx.x; idx < 18 * 16; idx += 256) {
    int r = idx >> 4, c = idx & 15;
    h1s[(r * 51 + (c >> 3) * 50) * 8 + (c & 7)] = 0.f;
  }
  __syncthreads();
  const int row = threadIdx.x >> 4, mg = threadIdx.x & 15;
  const int m0 = mg * 3;
  const int mlim = (mg == 15) ? 4 : 3;
  float a2[4][8];
#pragma unroll
  for (int mi = 0; mi < 4; ++mi)
#pragma unroll
    for (int o = 0; o < 8; ++o) a2[mi][o] = 0.f;
#pragma unroll
  for (int dr = 0; dr < 3; ++dr) {
    float win[48];
    const float* src = &h1s[((row + dr) * 51 + m0) * 8];
#pragma unroll
    for (int k = 0; k < 12; ++k)
      *(float4*)&win[k * 4] = *(const float4*)(src + k * 4);
#pragma unroll
    for (int o = 0; o < 8; ++o) {
      float wa = dww[(g * 8 + o) * 9 + dr * 3 + 0];
      float wb = dww[(g * 8 + o) * 9 + dr * 3 + 1];
      float wc = dww[(g * 8 + o) * 9 + dr * 3 + 2];
#pragma unroll
      for (int mi = 0; mi < 4; ++mi)
        a2[mi][o] += win[mi * 8 + o] * wa + win[(mi + 1) * 8 + o] * wb + win[(mi + 2) * 8 + o] * wc;
    }
  }
  float s0 = 0.f, q0 = 0.f;
#pragma unroll
  for (int mi = 0; mi < 4; ++mi) {
    if (mi < mlim) {
#pragma unroll
      for (int o = 0; o < 8; ++o) { s0 += a2[mi][o]; q0 += a2[mi][o] * a2[mi][o]; }
    }
  }
  int lane = threadIdx.x & 63, wvid = threadIdx.x >> 6;
#pragma unroll
  for (int off = 32; off; off >>= 1) { s0 += __shfl_down(s0, off, 64); q0 += __shfl_down(q0, off, 64); }
  if (lane == 0) { red[wvid][0] = s0; red[wvid][1] = q0; }
  __syncthreads();
  if (threadIdx.x < 2) {
    float t = red[0][threadIdx.x] + red[1][threadIdx.x] + red[2][threadIdx.x] + red[3][threadIdx.x];
    atomicAdd(&gn2sums[b * 6 + g * 2 + threadIdx.x], t);
  }
  if (STORE) {
    uint32_t* a2s = (uint32_t*)h1s;
#pragma unroll
    for (int mi = 0; mi < 4; ++mi) {
      if (mi < mlim) {
        uint32_t pk[4];
#pragma unroll
        for (int q = 0; q < 4; ++q)
          pk[q] = (uint32_t)f2h(a2[mi][2*q]) | ((uint32_t)f2h(a2[mi][2*q+1]) << 16);
        *(uint4*)&a2s[(row * NK_ + m0 + mi) * 4] = make_uint4(pk[0], pk[1], pk[2], pk[3]);
      }
    }
    __syncthreads();
    uint16_t* dstb = a2buf + ((size_t)(b * 3 + g) * POS_ + (size_t)n0 * NK_) * 8;
    for (int idx = threadIdx.x; idx < 16 * NK_; idx += 256)
      *(uint4*)(dstb + (size_t)idx * 8) = *(const uint4*)&a2s[idx * 4];
  }
}

// ---------------------------------------------------------------------------
// 7b-BIG) elementwise: a2 fp16 -> gn2 affine+swish -> 24->8 reduce -> rbuf
// ---------------------------------------------------------------------------
__global__ __launch_bounds__(256) void k_dla1b(const uint16_t* __restrict__ a2buf,
    const float* __restrict__ gn2ab, const float* __restrict__ rww,
    float* __restrict__ gn3sums, uint16_t* __restrict__ rbuf) {
  const int b = blockIdx.y;
  const int pos = blockIdx.x * 256 + threadIdx.x;
  __shared__ float rws[192];
  __shared__ float red[4][2];
  for (int i = threadIdx.x; i < 192; i += 256) rws[i] = rww[i];
  __syncthreads();
  float r[8] = {0.f,0.f,0.f,0.f,0.f,0.f,0.f,0.f};
  if (pos < POS_) {
#pragma unroll
    for (int g = 0; g < 3; ++g) {
      const float* ab = gn2ab + (b * 3 + g) * 16;
      uint4 v = *(const uint4*)(a2buf + ((size_t)(b * 3 + g) * POS_ + pos) * 8);
      uint32_t w[4] = {v.x, v.y, v.z, v.w};
#pragma unroll
      for (int q = 0; q < 4; ++q) {
#pragma unroll
        for (int hl = 0; hl < 2; ++hl) {
          int o = q * 2 + hl;
          float f = h2f((uint16_t)(hl ? (w[q] >> 16) : (w[q] & 0xFFFFu)));
          float sw = swishf(f * ab[o] + ab[8 + o]);
#pragma unroll
          for (int p = 0; p < 8; ++p) r[p] += rws[p * HID_ + g * 8 + o] * sw;
        }
      }
    }
  }
  float sr = 0.f, qr = 0.f;
#pragma unroll
  for (int p = 0; p < 8; ++p) { sr += r[p]; qr += r[p] * r[p]; }
  int lane = threadIdx.x & 63, wvid = threadIdx.x >> 6;
#pragma unroll
  for (int off = 32; off; off >>= 1) { sr += __shfl_down(sr, off, 64); qr += __shfl_down(qr, off, 64); }
  if (lane == 0) { red[wvid][0] = sr; red[wvid][1] = qr; }
  __syncthreads();
  if (threadIdx.x < 2) {
    float t = red[0][threadIdx.x] + red[1][threadIdx.x] + red[2][threadIdx.x] + red[3][threadIdx.x];
    atomicAdd(&gn3sums[b * 2 + threadIdx.x], t);
  }
  if (pos < POS_) {
    int n = pos / NK_, m = pos - n * NK_;
    uint16_t* dst = rbuf + ((size_t)b * N_ + n) * J_;
#pragma unroll
    for (int p = 0; p < 8; ++p) dst[p * JP_ + m] = f2bf(r[p]);
    if (m < 3) {
#pragma unroll
      for (int p = 0; p < 8; ++p) dst[p * JP_ + 49 + m] = 0;
    }
  }
}

// ---------------------------------------------------------------------------
// 7b-SMALL) fallback: recompute path (fp16 attn planes), precomputed affines
// ---------------------------------------------------------------------------
__global__ __launch_bounds__(256) void k_dla1s(const uint16_t* __restrict__ attn,
    const float* __restrict__ ew, const float* __restrict__ gn1ab,
    const float* __restrict__ dww, const float* __restrict__ gn2ab,
    const float* __restrict__ rww, float* __restrict__ gn3sums,
    uint16_t* __restrict__ rbuf) {
  const int nt = blockIdx.x, b = blockIdx.y;
  const int n0 = nt * 16;
  __shared__ __align__(16) float h1s[18 * 51 * 8];
  __shared__ float red[4][2];
  const int row = threadIdx.x >> 4, mg = threadIdx.x & 15;
  const int m0 = mg * 3;
  const int mlim = (mg == 15) ? 4 : 3;
  float racc[4][8];
#pragma unroll
  for (int mi = 0; mi < 4; ++mi)
#pragma unroll
    for (int p = 0; p < 8; ++p) racc[mi][p] = 0.f;

  for (int g = 0; g < 3; ++g) {
    float al[8], be[8], al2[8], be2[8];
    {
      const float* ab1 = gn1ab + (b * 3 + g) * 16;
      const float* ab2 = gn2ab + (b * 3 + g) * 16;
#pragma unroll
      for (int o = 0; o < 8; ++o) {
        al[o] = ab1[o]; be[o] = ab1[8 + o];
        al2[o] = ab2[o]; be2[o] = ab2[8 + o];
      }
    }
    __syncthreads();
    for (int task = threadIdx.x; task < 18 * NK_; task += 256) {
      int r = task / NK_, m = task % NK_;
      int n = n0 - 1 + r;
      float h1v[8];
      if (n < 0 || n >= N_) {
#pragma unroll
        for (int o = 0; o < 8; ++o) h1v[o] = 0.f;
      } else {
        float a[8];
        ld_attn8(attn, (((size_t)b * N_ + n) * NK_ + m) * 4, a);
#pragma unroll
        for (int o = 0; o < 8; ++o) {
          float v = 0.f;
#pragma unroll
          for (int h = 0; h < 8; ++h) v += ew[(g * 8 + o) * 8 + h] * a[h];
          h1v[o] = swishf(v * al[o] + be[o]);
        }
      }
      float* dst = &h1s[(r * 51 + m + 1) * 8];
      *(float4*)dst = make_float4(h1v[0], h1v[1], h1v[2], h1v[3]);
      *(float4*)(dst + 4) = make_float4(h1v[4], h1v[5], h1v[6], h1v[7]);
    }
    for (int idx = threadIdx.x; idx < 18 * 16; idx += 256) {
      int r = idx >> 4, c = idx & 15;
      h1s[(r * 51 + (c >> 3) * 50) * 8 + (c & 7)] = 0.f;
    }
    __syncthreads();
    float a2[4][8];
#pragma unroll
    for (int mi = 0; mi < 4; ++mi)
#pragma unroll
      for (int o = 0; o < 8; ++o) a2[mi][o] = 0.f;
#pragma unroll
    for (int dr = 0; dr < 3; ++dr) {
      float win[48];
      const float* src = &h1s[((row + dr) * 51 + m0) * 8];
#pragma unroll
      for (int k = 0; k < 12; ++k)
        *(float4*)&win[k * 4] = *(const float4*)(src + k * 4);
#pragma unroll
      for (int o = 0; o < 8; ++o) {
        float wa = dww[(g * 8 + o) * 9 + dr * 3 + 0];
        float wb = dww[(g * 8 + o) * 9 + dr * 3 + 1];
        float wc = dww[(g * 8 + o) * 9 + dr * 3 + 2];
#pragma unroll
        for (int mi = 0; mi < 4; ++mi)
          a2[mi][o] += win[mi * 8 + o] * wa + win[(mi + 1) * 8 + o] * wb + win[(mi + 2) * 8 + o] * wc;
      }
    }
#pragma unroll
    for (int mi = 0; mi < 4; ++mi) {
      if (mi < mlim) {
#pragma unroll
        for (int o = 0; o < 8; ++o) {
          float sw = swishf(a2[mi][o] * al2[o] + be2[o]);
#pragma unroll
          for (int p = 0; p < 8; ++p) racc[mi][p] += rww[p * HID_ + g * 8 + o] * sw;
        }
      }
    }
  }
  float sr = 0.f, qr = 0.f;
  const int n = n0 + row;
  uint16_t* dstbase = rbuf + ((size_t)b * N_ + n) * J_;
#pragma unroll
  for (int mi = 0; mi < 4; ++mi) {
    if (mi < mlim) {
      int m = m0 + mi;
#pragma unroll
      for (int p = 0; p < 8; ++p) {
        float v = racc[mi][p];
        dstbase[p * JP_ + m] = f2bf(v);
        sr += v; qr += v * v;
      }
    }
  }
  if (mg == 15) {
#pragma unroll
    for (int p = 0; p < 8; ++p) {
      dstbase[p * JP_ + 49] = 0; dstbase[p * JP_ + 50] = 0; dstbase[p * JP_ + 51] = 0;
    }
  }
  int lane = threadIdx.x & 63, wvid = threadIdx.x >> 6;
#pragma unroll
  for (int off = 32; off; off >>= 1) { sr += __shfl_down(sr, off, 64); qr += __shfl_down(qr, off, 64); }
  if (lane == 0) { red[wvid][0] = sr; red[wvid][1] = qr; }
  __syncthreads();
  if (threadIdx.x < 2) {
    float t = red[0][threadIdx.x] + red[1][threadIdx.x] + red[2][threadIdx.x] + red[3][threadIdx.x];
    atomicAdd(&gn3sums[b * 2 + threadIdx.x], t);
  }
}

// ---------------------------------------------------------------------------
// 8) GEMM2: out[b][n][c'] = sum_j gn3(r)[n][j] * wvT[b][c'][j] + proj_b[c']
// ---------------------------------------------------------------------------
__global__ __launch_bounds__(256) void k_out(const uint16_t* __restrict__ rr,
    const uint16_t* __restrict__ wvT, const float* __restrict__ gn3sums,
    const float* __restrict__ gn3_s, const float* __restrict__ gn3_b,
    const float* __restrict__ proj_b, float* __restrict__ outp) {
  const int mt = blockIdx.x, ct = blockIdx.y, b = blockIdx.z;
  const int n0 = mt * 64, c0 = ct * 128;
  const int tid = threadIdx.x, wvid = tid >> 6, lane = tid & 63;
  __shared__ __align__(16) uint32_t A32[64 * 20];
  __shared__ __align__(16) uint32_t B32[128 * 20];
  __shared__ float ab3[J_ * 2];
  {
    float ssum = gn3sums[b*2], sq = gn3sums[b*2+1];
    float mean = ssum * (1.f / CNT_);
    float var = sq * (1.f / CNT_) - mean * mean;
    float inv = rsqrtf(var + EPS_);
    for (int j = tid; j < J_; j += 256) {
      int h = j / JP_;
      float al = inv * gn3_s[h];
      ab3[j*2] = al; ab3[j*2+1] = gn3_b[h] - mean * al;
    }
  }
  floatx4 acc[8];
#pragma unroll
  for (int t = 0; t < 8; ++t) acc[t] = (floatx4){0.f,0.f,0.f,0.f};
  const int an = tid >> 2, acp = tid & 3;
  for (int ks = 0; ks < 13; ++ks) {
    const int k0 = ks * 32;
    __syncthreads();
    {
      const uint16_t* src = rr + ((size_t)b * N_ + n0 + an) * J_ + k0 + acp * 8;
      uint4 v = *(const uint4*)src;
      uint32_t raw[4] = {v.x, v.y, v.z, v.w};
      uint32_t pk[4];
#pragma unroll
      for (int jj = 0; jj < 4; ++jj) {
        int j = k0 + acp * 8 + jj * 2;
        float f0 = bf2f((uint16_t)(raw[jj] & 0xFFFFu)) * ab3[j*2]     + ab3[j*2+1];
        float f1 = bf2f((uint16_t)(raw[jj] >> 16))     * ab3[(j+1)*2] + ab3[(j+1)*2+1];
        pk[jj] = (uint32_t)f2bf(f0) | ((uint32_t)f2bf(f1) << 16);
      }
      *(uint4*)&A32[an * 20 + acp * 4] = make_uint4(pk[0], pk[1], pk[2], pk[3]);
    }
    for (int idx = tid; idx < 128 * 4; idx += 256) {
      int rw2 = idx >> 2, q = idx & 3;
      uint4 v = *(const uint4*)(wvT + ((size_t)b * C_ + c0 + rw2) * J_ + k0 + q * 8);
      *(uint4*)&B32[rw2 * 20 + q * 4] = v;
    }
    __syncthreads();
    short8 af = *(const short8*)&A32[(wvid * 16 + (lane & 15)) * 20 + (lane >> 4) * 4];
#pragma unroll
    for (int t = 0; t < 8; ++t) {
      short8 bfb = *(const short8*)&B32[(t * 16 + (lane & 15)) * 20 + (lane >> 4) * 4];
      acc[t] = __builtin_amdgcn_mfma_f32_16x16x32_bf16(af, bfb, acc[t], 0, 0, 0);
    }
  }
  const int rb = wvid * 16 + ((lane >> 4) << 2);
#pragma unroll
  for (int t = 0; t < 8; ++t) {
    int c = c0 + t * 16 + (lane & 15);
    float pb = proj_b[c];
#pragma unroll
    for (int r2 = 0; r2 < 4; ++r2)
      outp[((size_t)b * N_ + n0 + rb + r2) * C_ + c] = acc[t][r2] + pb;
  }
}

// ---------------------------------------------------------------------------
extern "C" void kernel_launch(void* const* d_in, const int* in_sizes, int n_in,
                              void* d_out, int out_size, void* d_ws, size_t ws_size,
                              hipStream_t stream) {
  (void)in_sizes; (void)n_in; (void)out_size;
  const float* x      = (const float*)d_in[0];
  const float* q_w    = (const float*)d_in[1];
  const float* down_w = (const float*)d_in[2];
  const float* kv_w   = (const float*)d_in[3];
  const float* proj_w = (const float*)d_in[4];
  const float* proj_b = (const float*)d_in[5];
  const float* rel_b  = (const float*)d_in[6];
  const float* ew     = (const float*)d_in[7];
  const float* gn1_s  = (const float*)d_in[8];
  const float* gn1_b  = (const float*)d_in[9];
  const float* dw_w   = (const float*)d_in[10];
  const float* gn2_s  = (const float*)d_in[11];
  const float* gn2_b  = (const float*)d_in[12];
  const float* red_w  = (const float*)d_in[13];
  const float* gn3_s  = (const float*)d_in[14];
  const float* gn3_b  = (const float*)d_in[15];
  float* outp = (float*)d_out;

  // Early region (both paths): xbf@0 (51,380,224); kvxbf@51,380,224 (802,816);
  //   kv@52,183,040 (3,211,264); wqkT@55,394,304 (8,388,608 slot) -> 63,782,912
  // BIG: a2@0 (118,013,952, overlaps dead early region);
  //   attn@118,013,952 (39,337,984 two planes); wvT@157,351,936 (6,815,744);
  //   rbuf@164,167,680 (41,746,432); stats@205,914,112 -> NEED_BIG = 205,924,352
  // SMALL: wvT@63,782,912; attn@70,598,656 (39,337,984);
  //   stats@109,936,640 -> NEED_SMALL = 109,946,880; rbuf@0 (aliases dead xbf)
  const size_t NEED_SMALL = 109946880;
  const size_t NEED_BIG   = 205924352;
  if (ws_size < NEED_SMALL) return;
  const bool big = (ws_size >= NEED_BIG);

  char* ws = (char*)d_ws;
  uint16_t* xbf   = (uint16_t*)(ws);
  uint16_t* kvxbf = (uint16_t*)(ws + 51380224);
  float*    kv    = (float*)(ws + 52183040);
  uint16_t* wqkT  = (uint16_t*)(ws + 55394304);
  uint16_t* a2    = (uint16_t*)(ws);             // big only
  uint16_t* attn;
  uint16_t* wvT;
  uint16_t* rbuf;
  float*    stats;
  if (big) {
    attn  = (uint16_t*)(ws + 118013952);
    wvT   = (uint16_t*)(ws + 157351936);
    rbuf  = (uint16_t*)(ws + 164167680);
    stats = (float*)(ws + 205914112);
  } else {
    wvT   = (uint16_t*)(ws + 63782912);
    attn  = (uint16_t*)(ws + 70598656);
    rbuf  = (uint16_t*)(ws);                     // aliases dead xbf
    stats = (float*)(ws + 109936640);
  }
  float* moms    = stats;           // 16*44 floats
  float* gn2sums = stats + 704;     // 16*6
  float* gn3sums = stats + 800;     // 16*2
  float* gn1ab   = stats + 1024;    // 48*16
  float* gn2ab   = stats + 1792;    // 48*16

  hipMemsetAsync(stats, 0, 4096, stream);
  k_kvx<<<1568, 256, 0, stream>>>(x, down_w, kvxbf, xbf);
  k_kv<<<dim3(16, 16), 256, 0, stream>>>(kvxbf, kv_w, kv);
  k_wqkv<<<dim3(16, 8, 2), 256, 0, stream>>>(kv, q_w, proj_w, wqkT, wvT);
  k_attn<<<dim3(49, 16), 256, 0, stream>>>(xbf, wqkT, rel_b, attn);
  k_moms<<<dim3(49, 16), 256, 0, stream>>>(attn, moms);
  k_aff<<<1, 64, 0, stream>>>(moms, ew, gn1_s, gn1_b, gn1ab);
  if (big) {
    k_dla0_t<true><<<dim3(196, 16, 3), 256, 0, stream>>>(attn, ew, gn1ab, dw_w,
                                                         gn2sums, a2);
    k_aff2<<<1, 64, 0, stream>>>(gn2sums, gn2_s, gn2_b, gn2ab);
    k_dla1b<<<dim3(601, 16), 256, 0, stream>>>(a2, gn2ab, red_w, gn3sums, rbuf);
  } else {
    k_dla0_t<false><<<dim3(196, 16, 3), 256, 0, stream>>>(attn, ew, gn1ab, dw_w,
                                                          gn2sums, nullptr);
    k_aff2<<<1, 64, 0, stream>>>(gn2sums, gn2_s, gn2_b, gn2ab);
    k_dla1s<<<dim3(196, 16), 256, 0, stream>>>(attn, ew, gn1ab, dw_w, gn2ab,
                                               red_w, gn3sums, rbuf);
  }
  k_out<<<dim3(49, 4, 16), 256, 0, stream>>>(rbuf, wvT, gn3sums, gn3_s, gn3_b, proj_b, outp);
}

// Round 9
// 750.492 us; speedup vs baseline: 1.0486x; 1.0486x over previous
//
#include <hip/hip_runtime.h>
#include <hip/hip_bf16.h>
#include <stdint.h>

// Problem constants
#define B_    16
#define C_    512
#define HIMG  56
#define N_    3136
#define NK_   49
#define NH_   8
#define HD_   64
#define JP_   52          // padded NK (49 -> 52) so 8*52 = 416 = 13*32
#define J_    416
#define HID_  24
#define POS_  153664      // N_ * NK_
#define PLH_  9834496     // u16 elems per attn head-plane: B_*N_*NK_*4
#define CNT_  1229312.0f  // 8 * 3136 * 49 (elements per group-norm group)
#define EPS_  1e-5f
#define SCALE_ 0.125f     // HEAD_DIM^-0.5

typedef __attribute__((ext_vector_type(8))) short short8;
typedef __attribute__((ext_vector_type(4))) float floatx4;

static __device__ __forceinline__ uint16_t f2bf(float f) {
  uint32_t u = __builtin_bit_cast(uint32_t, f);
  u = (u + 0x7FFFu + ((u >> 16) & 1u)) >> 16;
  return (uint16_t)u;
}
static __device__ __forceinline__ float bf2f(uint16_t h) {
  uint32_t u = ((uint32_t)h) << 16;
  return __builtin_bit_cast(float, u);
}
static __device__ __forceinline__ uint16_t f2h(float f) {
  _Float16 h = (_Float16)f;
  return __builtin_bit_cast(uint16_t, h);
}
static __device__ __forceinline__ float h2f(uint16_t u) {
  return (float)__builtin_bit_cast(_Float16, u);
}
static __device__ __forceinline__ float swishf(float z) {
  return z * __builtin_amdgcn_rcpf(1.f + __expf(-z));
}
// load 8 fp16 attn values for (b,n,m): 4 from each head-plane
static __device__ __forceinline__ void ld_attn8(const uint16_t* __restrict__ attn,
                                                size_t off, float* a) {
  uint2 v0 = *(const uint2*)(attn + off);
  uint2 v1 = *(const uint2*)(attn + PLH_ + off);
  a[0] = h2f((uint16_t)(v0.x & 0xFFFFu)); a[1] = h2f((uint16_t)(v0.x >> 16));
  a[2] = h2f((uint16_t)(v0.y & 0xFFFFu)); a[3] = h2f((uint16_t)(v0.y >> 16));
  a[4] = h2f((uint16_t)(v1.x & 0xFFFFu)); a[5] = h2f((uint16_t)(v1.x >> 16));
  a[6] = h2f((uint16_t)(v1.y & 0xFFFFu)); a[7] = h2f((uint16_t)(v1.y >> 16));
}

// gn1 affine (al,be) for group g's 8 channels from per-batch moments
static __device__ __forceinline__ void gn1_affine(const float* __restrict__ moms,
    const float* __restrict__ ew, const float* __restrict__ gs,
    const float* __restrict__ gb, int b, int g, float* al, float* be) {
  float m1[8];
#pragma unroll
  for (int h = 0; h < 8; ++h) m1[h] = moms[b * 44 + h];
  float sum = 0.f, ssq = 0.f;
#pragma unroll
  for (int o2 = 0; o2 < 8; ++o2) {
    int o = g * 8 + o2;
    float e[8];
#pragma unroll
    for (int h = 0; h < 8; ++h) e[h] = ew[o * 8 + h];
    float so = 0.f;
#pragma unroll
    for (int h = 0; h < 8; ++h) so += e[h] * m1[h];
    sum += so;
    int idx = 8;
#pragma unroll
    for (int h = 0; h < 8; ++h)
#pragma unroll
      for (int h2 = h; h2 < 8; ++h2) {
        float cf = e[h] * e[h2] * ((h == h2) ? 1.f : 2.f);
        ssq += cf * moms[b * 44 + idx];
        ++idx;
      }
  }
  float mean = sum * (1.f / CNT_);
  float var = ssq * (1.f / CNT_) - mean * mean;
  float inv = rsqrtf(var + EPS_);
#pragma unroll
  for (int o2 = 0; o2 < 8; ++o2) {
    al[o2] = inv * gs[g * 8 + o2];
    be[o2] = gb[g * 8 + o2] - mean * al[o2];
  }
}

// ---------------------------------------------------------------------------
// 1) kvxbf[b][m][c] (bf16) = depthwise 8x8/stride-8 downsample; also xbf
// ---------------------------------------------------------------------------
__global__ __launch_bounds__(256) void k_kvx(const float* __restrict__ x,
                                             const float* __restrict__ dw,
                                             uint16_t* __restrict__ kvxbf,
                                             uint16_t* __restrict__ xbf) {
  int g = blockIdx.x * 256 + threadIdx.x;
  int b = g / (C_ * NK_);
  int rem = g % (C_ * NK_);
  int c = rem / NK_;
  int m = rem % NK_;
  int ph = m / 7, pw = m % 7;
  const size_t base = ((size_t)(b * C_ + c)) * N_ + (ph * 8) * HIMG + pw * 8;
  const float* xp = x + base;
  uint16_t* xbp = xbf + base;
  const float* wp = dw + c * 64;
  float acc = 0.f;
#pragma unroll
  for (int i = 0; i < 8; ++i) {
    float4 a  = *(const float4*)(xp + i * HIMG);
    float4 bq = *(const float4*)(xp + i * HIMG + 4);
    acc += a.x*wp[i*8+0] + a.y*wp[i*8+1] + a.z*wp[i*8+2] + a.w*wp[i*8+3]
         + bq.x*wp[i*8+4] + bq.y*wp[i*8+5] + bq.z*wp[i*8+6] + bq.w*wp[i*8+7];
    uint32_t q0 = (uint32_t)f2bf(a.x)  | ((uint32_t)f2bf(a.y)  << 16);
    uint32_t q1 = (uint32_t)f2bf(a.z)  | ((uint32_t)f2bf(a.w)  << 16);
    uint32_t q2 = (uint32_t)f2bf(bq.x) | ((uint32_t)f2bf(bq.y) << 16);
    uint32_t q3 = (uint32_t)f2bf(bq.z) | ((uint32_t)f2bf(bq.w) << 16);
    *(uint4*)(xbp + (size_t)i * HIMG) = make_uint4(q0, q1, q2, q3);
  }
  kvxbf[((size_t)(b * NK_ + m)) * C_ + c] = f2bf(acc);
}

// ---------------------------------------------------------------------------
// 2) kv[b][m][col] = sum_c kvx[b][m][c] * kv_w[c][col]  -- MFMA bf16
// ---------------------------------------------------------------------------
__global__ __launch_bounds__(256) void k_kv(const uint16_t* __restrict__ kvxbf,
                                            const float* __restrict__ kv_w,
                                            float* __restrict__ kv) {
  const int ct = blockIdx.x, b = blockIdx.y;
  const int j0 = ct * 64;
  const int tid = threadIdx.x, wvid = tid >> 6, lane = tid & 63;
  __shared__ __align__(16) uint32_t A32[64 * 20];
  __shared__ __align__(16) uint32_t B32[64 * 20];
  floatx4 acc[4];
#pragma unroll
  for (int t = 0; t < 4; ++t) acc[t] = (floatx4){0.f,0.f,0.f,0.f};
  const int am = tid & 63, ak = tid >> 6;
  const int bj = tid & 63, bk = tid >> 6;
  for (int ks = 0; ks < 16; ++ks) {
    const int c0 = ks * 32;
    __syncthreads();
    {
      uint4 av = make_uint4(0, 0, 0, 0);
      if (am < NK_)
        av = *(const uint4*)(kvxbf + ((size_t)(b * NK_ + am)) * C_ + c0 + ak * 8);
      *(uint4*)&A32[am * 20 + ak * 4] = av;
    }
    {
      uint32_t pk[4];
#pragma unroll
      for (int r = 0; r < 4; ++r) {
        float f0 = kv_w[(size_t)(c0 + bk * 8 + 2 * r)     * 1024 + j0 + bj];
        float f1 = kv_w[(size_t)(c0 + bk * 8 + 2 * r + 1) * 1024 + j0 + bj];
        pk[r] = (uint32_t)f2bf(f0) | ((uint32_t)f2bf(f1) << 16);
      }
      *(uint4*)&B32[bj * 20 + bk * 4] = make_uint4(pk[0], pk[1], pk[2], pk[3]);
    }
    __syncthreads();
    short8 af = *(const short8*)&A32[(wvid * 16 + (lane & 15)) * 20 + (lane >> 4) * 4];
#pragma unroll
    for (int t = 0; t < 4; ++t) {
      short8 bfb = *(const short8*)&B32[(t * 16 + (lane & 15)) * 20 + (lane >> 4) * 4];
      acc[t] = __builtin_amdgcn_mfma_f32_16x16x32_bf16(af, bfb, acc[t], 0, 0, 0);
    }
  }
  const int rb = wvid * 16 + ((lane >> 4) << 2), cb = lane & 15;
#pragma unroll
  for (int t = 0; t < 4; ++t)
#pragma unroll
    for (int r2 = 0; r2 < 4; ++r2) {
      int m = rb + r2;
      if (m < NK_)
        kv[((size_t)(b * NK_ + m)) * 1024 + j0 + t * 16 + cb] = acc[t][r2];
    }
}

// ---------------------------------------------------------------------------
// 3+4 merged) z=0: wqkT[b][h*52+m][c] = SCALE*sum_d q_w[c][h*64+d]*k[b][h][m][d]
//             z=1: wvT[b][c'][h*52+m] = sum_d v[b][h][m][d]*proj_w[h*64+d][c']
// ---------------------------------------------------------------------------
__global__ __launch_bounds__(256) void k_wqkv(const float* __restrict__ kv,
                                              const float* __restrict__ q_w,
                                              const float* __restrict__ proj_w,
                                              uint16_t* __restrict__ wqkT,
                                              uint16_t* __restrict__ wvT) {
  int b = blockIdx.x, h = blockIdx.y;
  __shared__ float sm[56 * 64];
  if (blockIdx.z == 0) {
    for (int idx = threadIdx.x; idx < 56 * 64; idx += 256) {
      int m = idx >> 6, d = idx & 63;
      sm[idx] = (m < NK_) ? kv[((size_t)(b * NK_ + m)) * 1024 + h * HD_ + d] : 0.f;
    }
    __syncthreads();
#pragma unroll
    for (int cc = 0; cc < 2; ++cc) {
      int c = threadIdx.x + cc * 256;
      float qrow[64];
      const float* qp = q_w + (size_t)c * C_ + h * HD_;
#pragma unroll
      for (int d = 0; d < 64; ++d) qrow[d] = qp[d];
      for (int mc = 0; mc < NK_; mc += 8) {
        int cnt = min(8, NK_ - mc);
        float acc[8] = {0,0,0,0,0,0,0,0};
        for (int d = 0; d < 64; ++d) {
          float q = qrow[d];
#pragma unroll
          for (int i = 0; i < 8; ++i) acc[i] += q * sm[(mc + i) * 64 + d];
        }
        for (int i = 0; i < cnt; ++i)
          wqkT[((size_t)(b * J_ + h * JP_ + mc + i)) * C_ + c] = f2bf(acc[i] * SCALE_);
      }
    }
    for (int idx = threadIdx.x; idx < 3 * C_; idx += 256) {
      int rr = idx / C_, c = idx % C_;
      wqkT[((size_t)(b * J_ + h * JP_ + 49 + rr)) * C_ + c] = 0;
    }
  } else {
    for (int idx = threadIdx.x; idx < 56 * 64; idx += 256) {
      int m = idx >> 6, d = idx & 63;
      sm[idx] = (m < NK_) ? kv[((size_t)(b * NK_ + m)) * 1024 + 512 + h * HD_ + d] : 0.f;
    }
    __syncthreads();
#pragma unroll
    for (int cc = 0; cc < 2; ++cc) {
      int c = threadIdx.x + cc * 256;
      for (int mc = 0; mc < NK_; mc += 8) {
        int cnt = min(8, NK_ - mc);
        float acc[8] = {0,0,0,0,0,0,0,0};
        for (int d = 0; d < 64; ++d) {
          float w = proj_w[(size_t)(h * HD_ + d) * C_ + c];
#pragma unroll
          for (int i = 0; i < 8; ++i) acc[i] += sm[(mc + i) * 64 + d] * w;
        }
        uint16_t* dst = wvT + ((size_t)(b * C_ + c)) * J_ + h * JP_ + mc;
        if (cnt == 8) {
          uint32_t pk[4];
#pragma unroll
          for (int i = 0; i < 4; ++i)
            pk[i] = (uint32_t)f2bf(acc[2*i]) | ((uint32_t)f2bf(acc[2*i+1]) << 16);
          *(uint2*)(dst)     = make_uint2(pk[0], pk[1]);
          *(uint2*)(dst + 4) = make_uint2(pk[2], pk[3]);
        } else {
          for (int i = 0; i < cnt; ++i) dst[i] = f2bf(acc[i]);
        }
      }
      uint16_t* pd = wvT + ((size_t)(b * C_ + c)) * J_ + h * JP_ + 49;
      pd[0] = 0; pd[1] = 0; pd[2] = 0;
    }
  }
}

// ---------------------------------------------------------------------------
// 5) GEMM1 + softmax (R7-proven: ct-split, J=416, LDS-row softmax,
//    fp16 two-plane coalesced output). 132 us measured.
// ---------------------------------------------------------------------------
__global__ __launch_bounds__(256) void k_attn(const uint16_t* __restrict__ xbf,
                                              const uint16_t* __restrict__ wqkT,
                                              const float* __restrict__ rel_bias,
                                              uint16_t* __restrict__ attn) {
  const int mt = blockIdx.x, ct = blockIdx.y, b = blockIdx.z;
  const int n0 = mt * 64, j0 = ct * 208;
  const int tid = threadIdx.x, wvid = tid >> 6, lane = tid & 63;
  __shared__ __align__(16) char smem[64 * 212 * 4];
  uint32_t* A32 = (uint32_t*)smem;          // [64][20]
  uint32_t* B32 = A32 + 64 * 20;            // [208][20]
  float* Ss = (float*)smem;                 // [64][212] epilogue (aliases stage)

  floatx4 acc[13];
#pragma unroll
  for (int t = 0; t < 13; ++t) acc[t] = (floatx4){0.f,0.f,0.f,0.f};

  const int an = tid & 63, acp = tid >> 6;
  for (int ks = 0; ks < 16; ++ks) {
    const int c0 = ks * 32;
    __syncthreads();
    {
      const uint16_t* xb = xbf + ((size_t)(b * C_ + c0 + acp * 8)) * N_ + n0 + an;
      uint32_t pk[4];
#pragma unroll
      for (int jj = 0; jj < 4; ++jj) {
        uint32_t f0 = xb[(size_t)(2*jj) * N_];
        uint32_t f1 = xb[(size_t)(2*jj+1) * N_];
        pk[jj] = f0 | (f1 << 16);
      }
      *(uint4*)&A32[an * 20 + acp * 4] = make_uint4(pk[0], pk[1], pk[2], pk[3]);
    }
    for (int idx = tid; idx < 832; idx += 256) {
      int jl = idx >> 2, q = idx & 3;
      uint4 v = *(const uint4*)(wqkT + ((size_t)b * J_ + j0 + jl) * C_ + c0 + q * 8);
      *(uint4*)&B32[jl * 20 + q * 4] = v;
    }
    __syncthreads();
    short8 af = *(const short8*)&A32[(wvid * 16 + (lane & 15)) * 20 + (lane >> 4) * 4];
#pragma unroll
    for (int t = 0; t < 13; ++t) {
      short8 bfb = *(const short8*)&B32[(16 * t + (lane & 15)) * 20 + (lane >> 4) * 4];
      acc[t] = __builtin_amdgcn_mfma_f32_16x16x32_bf16(af, bfb, acc[t], 0, 0, 0);
    }
  }
  __syncthreads();
  {
    const int rb = wvid * 16 + ((lane >> 4) << 2), cb = lane & 15;
#pragma unroll
    for (int t = 0; t < 13; ++t)
#pragma unroll
      for (int r2 = 0; r2 < 4; ++r2)
        Ss[(rb + r2) * 212 + t * 16 + cb] = acc[t][r2];
  }
  __syncthreads();
  {
    const int row = tid >> 2, hh = tid & 3;
    const int n = n0 + row;
    const float* bias = rel_bias + (size_t)n * NK_;
    float* srow = &Ss[row * 212 + hh * JP_];
    float mx = -1e30f;
    for (int m = 0; m < NK_; ++m) mx = fmaxf(mx, srow[m] + bias[m]);
    float sum = 0.f;
    for (int m = 0; m < NK_; ++m) { float e = __expf(srow[m] + bias[m] - mx); srow[m] = e; sum += e; }
    float inv = 1.f / sum;
    for (int m = 0; m < NK_; ++m) srow[m] *= inv;
  }
  __syncthreads();
  // coalesced write: plane ct, [b][n][49][4] fp16
  uint16_t* dst = attn + (size_t)ct * PLH_ + ((size_t)b * N_ + n0) * NK_ * 4;
  for (int task = tid; task < 64 * NK_; task += 256) {
    int row = task / NK_, m = task % NK_;
    const float* sr = &Ss[row * 212];
    uint32_t lo = (uint32_t)f2h(sr[m])         | ((uint32_t)f2h(sr[JP_ + m])   << 16);
    uint32_t hi = (uint32_t)f2h(sr[2*JP_ + m]) | ((uint32_t)f2h(sr[3*JP_ + m]) << 16);
    *(uint2*)(dst + (size_t)task * 4) = make_uint2(lo, hi);
  }
}

// ---------------------------------------------------------------------------
// 6) attn moments per batch (fp16 attn, two planes)
// ---------------------------------------------------------------------------
__global__ __launch_bounds__(256) void k_moms(const uint16_t* __restrict__ attn,
                                              float* __restrict__ moms) {
  int nt = blockIdx.x, b = blockIdx.y;
  float vals[44];
#pragma unroll
  for (int k = 0; k < 44; ++k) vals[k] = 0.f;
  for (int task = threadIdx.x; task < 64 * NK_; task += 256) {
    float a[8];
    ld_attn8(attn, ((size_t)b * N_ + nt * 64) * NK_ * 4 + (size_t)task * 4, a);
#pragma unroll
    for (int h = 0; h < 8; ++h) vals[h] += a[h];
    int idx = 8;
#pragma unroll
    for (int h = 0; h < 8; ++h)
#pragma unroll
      for (int h2 = h; h2 < 8; ++h2) { vals[idx] += a[h] * a[h2]; ++idx; }
  }
  __shared__ float red[4][44];
  int lane = threadIdx.x & 63, wvid = threadIdx.x >> 6;
#pragma unroll
  for (int k = 0; k < 44; ++k) {
#pragma unroll
    for (int off = 32; off; off >>= 1) vals[k] += __shfl_down(vals[k], off, 64);
  }
  if (lane == 0) {
#pragma unroll
    for (int k = 0; k < 44; ++k) red[wvid][k] = vals[k];
  }
  __syncthreads();
  if (threadIdx.x < 44) {
    float t = red[0][threadIdx.x] + red[1][threadIdx.x] + red[2][threadIdx.x] + red[3][threadIdx.x];
    atomicAdd(&moms[b * 44 + threadIdx.x], t);
  }
}

// ---------------------------------------------------------------------------
// 6b) gn1 affine precompute
// ---------------------------------------------------------------------------
__global__ void k_aff(const float* __restrict__ moms, const float* __restrict__ ew,
                      const float* __restrict__ gn1_s, const float* __restrict__ gn1_b,
                      float* __restrict__ gn1ab) {
  int t = threadIdx.x;
  if (t >= 48) return;
  int b = t / 3, g = t % 3;
  float al[8], be[8];
  gn1_affine(moms, ew, gn1_s, gn1_b, b, g, al, be);
#pragma unroll
  for (int o = 0; o < 8; ++o) { gn1ab[t * 16 + o] = al[o]; gn1ab[t * 16 + 8 + o] = be[o]; }
}

// ---------------------------------------------------------------------------
// 6c) gn2 affine precompute (after k_dla0)
// ---------------------------------------------------------------------------
__global__ void k_aff2(const float* __restrict__ gn2sums, const float* __restrict__ gn2_s,
                       const float* __restrict__ gn2_b, float* __restrict__ gn2ab) {
  int t = threadIdx.x;
  if (t >= 48) return;
  int b = t / 3, g = t % 3;
  float s2 = gn2sums[b * 6 + g * 2], q2 = gn2sums[b * 6 + g * 2 + 1];
  float mean = s2 * (1.f / CNT_);
  float var = q2 * (1.f / CNT_) - mean * mean;
  float inv = rsqrtf(var + EPS_);
#pragma unroll
  for (int o = 0; o < 8; ++o) {
    float al = inv * gn2_s[g * 8 + o];
    gn2ab[t * 16 + o] = al;
    gn2ab[t * 16 + 8 + o] = gn2_b[g * 8 + o] - mean * al;
  }
}

// ---------------------------------------------------------------------------
// 7a) DLA pass 0, ALL 3 GROUPS per block: attn tile staged to LDS ONCE
//     (fp16, bit-exact), then per g: h1 -> stencil -> gn2 sums (+a2 store).
// ---------------------------------------------------------------------------
template<bool STORE>
__global__ __launch_bounds__(256) void k_dla0_t(const uint16_t* __restrict__ attn,
    const float* __restrict__ ew, const float* __restrict__ gn1ab,
    const float* __restrict__ dww, float* __restrict__ gn2sums,
    uint16_t* __restrict__ a2buf) {
  const int nt = blockIdx.x, b = blockIdx.y;  // 196 x 16
  const int n0 = nt * 16;
  __shared__ __align__(16) uint32_t aS[18 * 49 * 4];   // 14112 B (fp16 x8/cell)
  __shared__ __align__(16) float h1s[18 * 51 * 8];     // 29376 B
  __shared__ float red[4][2];
  // stage attn tile once (rows n0-1..n0+16); OOB rows stay zero (branch below)
  for (int task = threadIdx.x; task < 18 * NK_; task += 256) {
    int r = task / NK_, m = task % NK_;
    int n = n0 - 1 + r;
    uint4 v = make_uint4(0, 0, 0, 0);
    if (n >= 0 && n < N_) {
      size_t off = (((size_t)b * N_ + n) * NK_ + m) * 4;
      uint2 v0 = *(const uint2*)(attn + off);
      uint2 v1 = *(const uint2*)(attn + PLH_ + off);
      v = make_uint4(v0.x, v0.y, v1.x, v1.y);
    }
    *(uint4*)&aS[task * 4] = v;
  }
  const int row = threadIdx.x >> 4, mg = threadIdx.x & 15;
  const int m0 = mg * 3;
  const int mlim = (mg == 15) ? 4 : 3;
  const int lane = threadIdx.x & 63, wvid = threadIdx.x >> 6;

  for (int g = 0; g < 3; ++g) {
    float al[8], be[8];
    {
      const float* ab = gn1ab + (b * 3 + g) * 16;
#pragma unroll
      for (int o = 0; o < 8; ++o) { al[o] = ab[o]; be[o] = ab[8 + o]; }
    }
    __syncthreads();   // aS staged (g=0) / prior g's a2s-alias reads done
    // phase A: h1 from LDS-staged attn
    for (int task = threadIdx.x; task < 18 * NK_; task += 256) {
      int r = task / NK_, m = task % NK_;
      int n = n0 - 1 + r;
      float h1v[8];
      if (n < 0 || n >= N_) {
#pragma unroll
        for (int o = 0; o < 8; ++o) h1v[o] = 0.f;
      } else {
        uint4 v = *(const uint4*)&aS[task * 4];
        float a[8];
        a[0] = h2f((uint16_t)(v.x & 0xFFFFu)); a[1] = h2f((uint16_t)(v.x >> 16));
        a[2] = h2f((uint16_t)(v.y & 0xFFFFu)); a[3] = h2f((uint16_t)(v.y >> 16));
        a[4] = h2f((uint16_t)(v.z & 0xFFFFu)); a[5] = h2f((uint16_t)(v.z >> 16));
        a[6] = h2f((uint16_t)(v.w & 0xFFFFu)); a[7] = h2f((uint16_t)(v.w >> 16));
#pragma unroll
        for (int o = 0; o < 8; ++o) {
          float v2 = 0.f;
#pragma unroll
          for (int h = 0; h < 8; ++h) v2 += ew[(g * 8 + o) * 8 + h] * a[h];
          h1v[o] = swishf(v2 * al[o] + be[o]);
        }
      }
      float* dst = &h1s[(r * 51 + m + 1) * 8];
      *(float4*)dst = make_float4(h1v[0], h1v[1], h1v[2], h1v[3]);
      *(float4*)(dst + 4) = make_float4(h1v[4], h1v[5], h1v[6], h1v[7]);
    }
    for (int idx = threadIdx.x; idx < 18 * 16; idx += 256) {
      int r = idx >> 4, c = idx & 15;
      h1s[(r * 51 + (c >> 3) * 50) * 8 + (c & 7)] = 0.f;
    }
    __syncthreads();
    // phase B: vectorized stencil
    float a2[4][8];
#pragma unroll
    for (int mi = 0; mi < 4; ++mi)
#pragma unroll
      for (int o = 0; o < 8; ++o) a2[mi][o] = 0.f;
#pragma unroll
    for (int dr = 0; dr < 3; ++dr) {
      float win[48];
      const float* src = &h1s[((row + dr) * 51 + m0) * 8];
#pragma unroll
      for (int k = 0; k < 12; ++k)
        *(float4*)&win[k * 4] = *(const float4*)(src + k * 4);
#pragma unroll
      for (int o = 0; o < 8; ++o) {
        float wa = dww[(g * 8 + o) * 9 + dr * 3 + 0];
        float wb = dww[(g * 8 + o) * 9 + dr * 3 + 1];
        float wc = dww[(g * 8 + o) * 9 + dr * 3 + 2];
#pragma unroll
        for (int mi = 0; mi < 4; ++mi)
          a2[mi][o] += win[mi * 8 + o] * wa + win[(mi + 1) * 8 + o] * wb + win[(mi + 2) * 8 + o] * wc;
      }
    }
    float s0 = 0.f, q0 = 0.f;
#pragma unroll
    for (int mi = 0; mi < 4; ++mi) {
      if (mi < mlim) {
#pragma unroll
        for (int o = 0; o < 8; ++o) { s0 += a2[mi][o]; q0 += a2[mi][o] * a2[mi][o]; }
      }
    }
#pragma unroll
    for (int off = 32; off; off >>= 1) { s0 += __shfl_down(s0, off, 64); q0 += __shfl_down(q0, off, 64); }
    if (lane == 0) { red[wvid][0] = s0; red[wvid][1] = q0; }
    __syncthreads();   // red visible AND all h1s stencil reads done
    if (threadIdx.x < 2) {
      float t = red[0][threadIdx.x] + red[1][threadIdx.x] + red[2][threadIdx.x] + red[3][threadIdx.x];
      atomicAdd(&gn2sums[b * 6 + g * 2 + threadIdx.x], t);
    }
    if (STORE) {
      uint32_t* a2s = (uint32_t*)h1s;   // alias safe: stencil reads done
#pragma unroll
      for (int mi = 0; mi < 4; ++mi) {
        if (mi < mlim) {
          uint32_t pk[4];
#pragma unroll
          for (int q = 0; q < 4; ++q)
            pk[q] = (uint32_t)f2h(a2[mi][2*q]) | ((uint32_t)f2h(a2[mi][2*q+1]) << 16);
          *(uint4*)&a2s[(row * NK_ + m0 + mi) * 4] = make_uint4(pk[0], pk[1], pk[2], pk[3]);
        }
      }
      __syncthreads();
      uint16_t* dstb = a2buf + ((size_t)(b * 3 + g) * POS_ + (size_t)n0 * NK_) * 8;
      for (int idx = threadIdx.x; idx < 16 * NK_; idx += 256)
        *(uint4*)(dstb + (size_t)idx * 8) = *(const uint4*)&a2s[idx * 4];
    }
  }
}

// ---------------------------------------------------------------------------
// 7b-BIG) elementwise: a2 fp16 -> gn2 affine+swish -> 24->8 reduce -> rbuf
// ---------------------------------------------------------------------------
__global__ __launch_bounds__(256) void k_dla1b(const uint16_t* __restrict__ a2buf,
    const float* __restrict__ gn2ab, const float* __restrict__ rww,
    float* __restrict__ gn3sums, uint16_t* __restrict__ rbuf) {
  const int b = blockIdx.y;
  const int pos = blockIdx.x * 256 + threadIdx.x;
  __shared__ float rws[192];
  __shared__ float red[4][2];
  for (int i = threadIdx.x; i < 192; i += 256) rws[i] = rww[i];
  __syncthreads();
  float r[8] = {0.f,0.f,0.f,0.f,0.f,0.f,0.f,0.f};
  if (pos < POS_) {
#pragma unroll
    for (int g = 0; g < 3; ++g) {
      const float* ab = gn2ab + (b * 3 + g) * 16;
      uint4 v = *(const uint4*)(a2buf + ((size_t)(b * 3 + g) * POS_ + pos) * 8);
      uint32_t w[4] = {v.x, v.y, v.z, v.w};
#pragma unroll
      for (int q = 0; q < 4; ++q) {
#pragma unroll
        for (int hl = 0; hl < 2; ++hl) {
          int o = q * 2 + hl;
          float f = h2f((uint16_t)(hl ? (w[q] >> 16) : (w[q] & 0xFFFFu)));
          float sw = swishf(f * ab[o] + ab[8 + o]);
#pragma unroll
          for (int p = 0; p < 8; ++p) r[p] += rws[p * HID_ + g * 8 + o] * sw;
        }
      }
    }
  }
  float sr = 0.f, qr = 0.f;
#pragma unroll
  for (int p = 0; p < 8; ++p) { sr += r[p]; qr += r[p] * r[p]; }
  int lane = threadIdx.x & 63, wvid = threadIdx.x >> 6;
#pragma unroll
  for (int off = 32; off; off >>= 1) { sr += __shfl_down(sr, off, 64); qr += __shfl_down(qr, off, 64); }
  if (lane == 0) { red[wvid][0] = sr; red[wvid][1] = qr; }
  __syncthreads();
  if (threadIdx.x < 2) {
    float t = red[0][threadIdx.x] + red[1][threadIdx.x] + red[2][threadIdx.x] + red[3][threadIdx.x];
    atomicAdd(&gn3sums[b * 2 + threadIdx.x], t);
  }
  if (pos < POS_) {
    int n = pos / NK_, m = pos - n * NK_;
    uint16_t* dst = rbuf + ((size_t)b * N_ + n) * J_;
#pragma unroll
    for (int p = 0; p < 8; ++p) dst[p * JP_ + m] = f2bf(r[p]);
    if (m < 3) {
#pragma unroll
      for (int p = 0; p < 8; ++p) dst[p * JP_ + 49 + m] = 0;
    }
  }
}

// ---------------------------------------------------------------------------
// 7b-SMALL) fallback: recompute path (fp16 attn planes), precomputed affines
// ---------------------------------------------------------------------------
__global__ __launch_bounds__(256) void k_dla1s(const uint16_t* __restrict__ attn,
    const float* __restrict__ ew, const float* __restrict__ gn1ab,
    const float* __restrict__ dww, const float* __restrict__ gn2ab,
    const float* __restrict__ rww, float* __restrict__ gn3sums,
    uint16_t* __restrict__ rbuf) {
  const int nt = blockIdx.x, b = blockIdx.y;
  const int n0 = nt * 16;
  __shared__ __align__(16) float h1s[18 * 51 * 8];
  __shared__ float red[4][2];
  const int row = threadIdx.x >> 4, mg = threadIdx.x & 15;
  const int m0 = mg * 3;
  const int mlim = (mg == 15) ? 4 : 3;
  float racc[4][8];
#pragma unroll
  for (int mi = 0; mi < 4; ++mi)
#pragma unroll
    for (int p = 0; p < 8; ++p) racc[mi][p] = 0.f;

  for (int g = 0; g < 3; ++g) {
    float al[8], be[8], al2[8], be2[8];
    {
      const float* ab1 = gn1ab + (b * 3 + g) * 16;
      const float* ab2 = gn2ab + (b * 3 + g) * 16;
#pragma unroll
      for (int o = 0; o < 8; ++o) {
        al[o] = ab1[o]; be[o] = ab1[8 + o];
        al2[o] = ab2[o]; be2[o] = ab2[8 + o];
      }
    }
    __syncthreads();
    for (int task = threadIdx.x; task < 18 * NK_; task += 256) {
      int r = task / NK_, m = task % NK_;
      int n = n0 - 1 + r;
      float h1v[8];
      if (n < 0 || n >= N_) {
#pragma unroll
        for (int o = 0; o < 8; ++o) h1v[o] = 0.f;
      } else {
        float a[8];
        ld_attn8(attn, (((size_t)b * N_ + n) * NK_ + m) * 4, a);
#pragma unroll
        for (int o = 0; o < 8; ++o) {
          float v = 0.f;
#pragma unroll
          for (int h = 0; h < 8; ++h) v += ew[(g * 8 + o) * 8 + h] * a[h];
          h1v[o] = swishf(v * al[o] + be[o]);
        }
      }
      float* dst = &h1s[(r * 51 + m + 1) * 8];
      *(float4*)dst = make_float4(h1v[0], h1v[1], h1v[2], h1v[3]);
      *(float4*)(dst + 4) = make_float4(h1v[4], h1v[5], h1v[6], h1v[7]);
    }
    for (int idx = threadIdx.x; idx < 18 * 16; idx += 256) {
      int r = idx >> 4, c = idx & 15;
      h1s[(r * 51 + (c >> 3) * 50) * 8 + (c & 7)] = 0.f;
    }
    __syncthreads();
    float a2[4][8];
#pragma unroll
    for (int mi = 0; mi < 4; ++mi)
#pragma unroll
      for (int o = 0; o < 8; ++o) a2[mi][o] = 0.f;
#pragma unroll
    for (int dr = 0; dr < 3; ++dr) {
      float win[48];
      const float* src = &h1s[((row + dr) * 51 + m0) * 8];
#pragma unroll
      for (int k = 0; k < 12; ++k)
        *(float4*)&win[k * 4] = *(const float4*)(src + k * 4);
#pragma unroll
      for (int o = 0; o < 8; ++o) {
        float wa = dww[(g * 8 + o) * 9 + dr * 3 + 0];
        float wb = dww[(g * 8 + o) * 9 + dr * 3 + 1];
        float wc = dww[(g * 8 + o) * 9 + dr * 3 + 2];
#pragma unroll
        for (int mi = 0; mi < 4; ++mi)
          a2[mi][o] += win[mi * 8 + o] * wa + win[(mi + 1) * 8 + o] * wb + win[(mi + 2) * 8 + o] * wc;
      }
    }
#pragma unroll
    for (int mi = 0; mi < 4; ++mi) {
      if (mi < mlim) {
#pragma unroll
        for (int o = 0; o < 8; ++o) {
          float sw = swishf(a2[mi][o] * al2[o] + be2[o]);
#pragma unroll
          for (int p = 0; p < 8; ++p) racc[mi][p] += rww[p * HID_ + g * 8 + o] * sw;
        }
      }
    }
  }
  float sr = 0.f, qr = 0.f;
  const int n = n0 + row;
  uint16_t* dstbase = rbuf + ((size_t)b * N_ + n) * J_;
#pragma unroll
  for (int mi = 0; mi < 4; ++mi) {
    if (mi < mlim) {
      int m = m0 + mi;
#pragma unroll
      for (int p = 0; p < 8; ++p) {
        float v = racc[mi][p];
        dstbase[p * JP_ + m] = f2bf(v);
        sr += v; qr += v * v;
      }
    }
  }
  if (mg == 15) {
#pragma unroll
    for (int p = 0; p < 8; ++p) {
      dstbase[p * JP_ + 49] = 0; dstbase[p * JP_ + 50] = 0; dstbase[p * JP_ + 51] = 0;
    }
  }
  int lane = threadIdx.x & 63, wvid = threadIdx.x >> 6;
#pragma unroll
  for (int off = 32; off; off >>= 1) { sr += __shfl_down(sr, off, 64); qr += __shfl_down(qr, off, 64); }
  if (lane == 0) { red[wvid][0] = sr; red[wvid][1] = qr; }
  __syncthreads();
  if (threadIdx.x < 2) {
    float t = red[0][threadIdx.x] + red[1][threadIdx.x] + red[2][threadIdx.x] + red[3][threadIdx.x];
    atomicAdd(&gn3sums[b * 2 + threadIdx.x], t);
  }
}

// ---------------------------------------------------------------------------
// 8) GEMM2: out[b][n][c'] = sum_j gn3(r)[n][j] * wvT[b][c'][j] + proj_b[c']
// ---------------------------------------------------------------------------
__global__ __launch_bounds__(256) void k_out(const uint16_t* __restrict__ rr,
    const uint16_t* __restrict__ wvT, const float* __restrict__ gn3sums,
    const float* __restrict__ gn3_s, const float* __restrict__ gn3_b,
    const float* __restrict__ proj_b, float* __restrict__ outp) {
  const int mt = blockIdx.x, ct = blockIdx.y, b = blockIdx.z;
  const int n0 = mt * 64, c0 = ct * 128;
  const int tid = threadIdx.x, wvid = tid >> 6, lane = tid & 63;
  __shared__ __align__(16) uint32_t A32[64 * 20];
  __shared__ __align__(16) uint32_t B32[128 * 20];
  __shared__ float ab3[J_ * 2];
  {
    float ssum = gn3sums[b*2], sq = gn3sums[b*2+1];
    float mean = ssum * (1.f / CNT_);
    float var = sq * (1.f / CNT_) - mean * mean;
    float inv = rsqrtf(var + EPS_);
    for (int j = tid; j < J_; j += 256) {
      int h = j / JP_;
      float al = inv * gn3_s[h];
      ab3[j*2] = al; ab3[j*2+1] = gn3_b[h] - mean * al;
    }
  }
  floatx4 acc[8];
#pragma unroll
  for (int t = 0; t < 8; ++t) acc[t] = (floatx4){0.f,0.f,0.f,0.f};
  const int an = tid >> 2, acp = tid & 3;
  for (int ks = 0; ks < 13; ++ks) {
    const int k0 = ks * 32;
    __syncthreads();
    {
      const uint16_t* src = rr + ((size_t)b * N_ + n0 + an) * J_ + k0 + acp * 8;
      uint4 v = *(const uint4*)src;
      uint32_t raw[4] = {v.x, v.y, v.z, v.w};
      uint32_t pk[4];
#pragma unroll
      for (int jj = 0; jj < 4; ++jj) {
        int j = k0 + acp * 8 + jj * 2;
        float f0 = bf2f((uint16_t)(raw[jj] & 0xFFFFu)) * ab3[j*2]     + ab3[j*2+1];
        float f1 = bf2f((uint16_t)(raw[jj] >> 16))     * ab3[(j+1)*2] + ab3[(j+1)*2+1];
        pk[jj] = (uint32_t)f2bf(f0) | ((uint32_t)f2bf(f1) << 16);
      }
      *(uint4*)&A32[an * 20 + acp * 4] = make_uint4(pk[0], pk[1], pk[2], pk[3]);
    }
    for (int idx = tid; idx < 128 * 4; idx += 256) {
      int rw2 = idx >> 2, q = idx & 3;
      uint4 v = *(const uint4*)(wvT + ((size_t)b * C_ + c0 + rw2) * J_ + k0 + q * 8);
      *(uint4*)&B32[rw2 * 20 + q * 4] = v;
    }
    __syncthreads();
    short8 af = *(const short8*)&A32[(wvid * 16 + (lane & 15)) * 20 + (lane >> 4) * 4];
#pragma unroll
    for (int t = 0; t < 8; ++t) {
      short8 bfb = *(const short8*)&B32[(t * 16 + (lane & 15)) * 20 + (lane >> 4) * 4];
      acc[t] = __builtin_amdgcn_mfma_f32_16x16x32_bf16(af, bfb, acc[t], 0, 0, 0);
    }
  }
  const int rb = wvid * 16 + ((lane >> 4) << 2);
#pragma unroll
  for (int t = 0; t < 8; ++t) {
    int c = c0 + t * 16 + (lane & 15);
    float pb = proj_b[c];
#pragma unroll
    for (int r2 = 0; r2 < 4; ++r2)
      outp[((size_t)b * N_ + n0 + rb + r2) * C_ + c] = acc[t][r2] + pb;
  }
}

// ---------------------------------------------------------------------------
extern "C" void kernel_launch(void* const* d_in, const int* in_sizes, int n_in,
                              void* d_out, int out_size, void* d_ws, size_t ws_size,
                              hipStream_t stream) {
  (void)in_sizes; (void)n_in; (void)out_size;
  const float* x      = (const float*)d_in[0];
  const float* q_w    = (const float*)d_in[1];
  const float* down_w = (const float*)d_in[2];
  const float* kv_w   = (const float*)d_in[3];
  const float* proj_w = (const float*)d_in[4];
  const float* proj_b = (const float*)d_in[5];
  const float* rel_b  = (const float*)d_in[6];
  const float* ew     = (const float*)d_in[7];
  const float* gn1_s  = (const float*)d_in[8];
  const float* gn1_b  = (const float*)d_in[9];
  const float* dw_w   = (const float*)d_in[10];
  const float* gn2_s  = (const float*)d_in[11];
  const float* gn2_b  = (const float*)d_in[12];
  const float* red_w  = (const float*)d_in[13];
  const float* gn3_s  = (const float*)d_in[14];
  const float* gn3_b  = (const float*)d_in[15];
  float* outp = (float*)d_out;

  // Early region (both paths): xbf@0 (51,380,224); kvxbf@51,380,224 (802,816);
  //   kv@52,183,040 (3,211,264); wqkT@55,394,304 (8,388,608 slot) -> 63,782,912
  // BIG: a2@0 (118,013,952, overlaps dead early region);
  //   attn@118,013,952 (39,337,984 two planes); wvT@157,351,936 (6,815,744);
  //   rbuf@164,167,680 (41,746,432); stats@205,914,112 -> NEED_BIG = 205,924,352
  // SMALL: wvT@63,782,912; attn@70,598,656 (39,337,984);
  //   stats@109,936,640 -> NEED_SMALL = 109,946,880; rbuf@0 (aliases dead xbf)
  const size_t NEED_SMALL = 109946880;
  const size_t NEED_BIG   = 205924352;
  if (ws_size < NEED_SMALL) return;
  const bool big = (ws_size >= NEED_BIG);

  char* ws = (char*)d_ws;
  uint16_t* xbf   = (uint16_t*)(ws);
  uint16_t* kvxbf = (uint16_t*)(ws + 51380224);
  float*    kv    = (float*)(ws + 52183040);
  uint16_t* wqkT  = (uint16_t*)(ws + 55394304);
  uint16_t* a2    = (uint16_t*)(ws);             // big only
  uint16_t* attn;
  uint16_t* wvT;
  uint16_t* rbuf;
  float*    stats;
  if (big) {
    attn  = (uint16_t*)(ws + 118013952);
    wvT   = (uint16_t*)(ws + 157351936);
    rbuf  = (uint16_t*)(ws + 164167680);
    stats = (float*)(ws + 205914112);
  } else {
    wvT   = (uint16_t*)(ws + 63782912);
    attn  = (uint16_t*)(ws + 70598656);
    rbuf  = (uint16_t*)(ws);                     // aliases dead xbf
    stats = (float*)(ws + 109936640);
  }
  float* moms    = stats;           // 16*44 floats
  float* gn2sums = stats + 704;     // 16*6
  float* gn3sums = stats + 800;     // 16*2
  float* gn1ab   = stats + 1024;    // 48*16
  float* gn2ab   = stats + 1792;    // 48*16

  hipMemsetAsync(stats, 0, 4096, stream);
  k_kvx<<<1568, 256, 0, stream>>>(x, down_w, kvxbf, xbf);
  k_kv<<<dim3(16, 16), 256, 0, stream>>>(kvxbf, kv_w, kv);
  k_wqkv<<<dim3(16, 8, 2), 256, 0, stream>>>(kv, q_w, proj_w, wqkT, wvT);
  k_attn<<<dim3(49, 2, 16), 256, 0, stream>>>(xbf, wqkT, rel_b, attn);
  k_moms<<<dim3(49, 16), 256, 0, stream>>>(attn, moms);
  k_aff<<<1, 64, 0, stream>>>(moms, ew, gn1_s, gn1_b, gn1ab);
  if (big) {
    k_dla0_t<true><<<dim3(196, 16), 256, 0, stream>>>(attn, ew, gn1ab, dw_w,
                                                      gn2sums, a2);
    k_aff2<<<1, 64, 0, stream>>>(gn2sums, gn2_s, gn2_b, gn2ab);
    k_dla1b<<<dim3(601, 16), 256, 0, stream>>>(a2, gn2ab, red_w, gn3sums, rbuf);
  } else {
    k_dla0_t<false><<<dim3(196, 16), 256, 0, stream>>>(attn, ew, gn1ab, dw_w,
                                                       gn2sums, nullptr);
    k_aff2<<<1, 64, 0, stream>>>(gn2sums, gn2_s, gn2_b, gn2ab);
    k_dla1s<<<dim3(196, 16), 256, 0, stream>>>(attn, ew, gn1ab, dw_w, gn2ab,
                                               red_w, gn3sums, rbuf);
  }
  k_out<<<dim3(49, 4, 16), 256, 0, stream>>>(rbuf, wvT, gn3sums, gn3_s, gn3_b, proj_b, outp);
}

// Round 10
// 722.496 us; speedup vs baseline: 1.0893x; 1.0387x over previous
//
#include <hip/hip_runtime.h>
#include <hip/hip_bf16.h>
#include <stdint.h>

// Problem constants
#define B_    16
#define C_    512
#define HIMG  56
#define N_    3136
#define NK_   49
#define NH_   8
#define HD_   64
#define JP_   52          // padded NK (49 -> 52) so 8*52 = 416 = 13*32
#define J_    416
#define SST_  213         // Ss epilogue row stride (odd -> conflict-free scalar)
#define HID_  24
#define POS_  153664      // N_ * NK_
#define PLH_  9834496     // u16 elems per attn head-plane: B_*N_*NK_*4
#define CNT_  1229312.0f  // 8 * 3136 * 49 (elements per group-norm group)
#define EPS_  1e-5f
#define SCALE_ 0.125f     // HEAD_DIM^-0.5

typedef __attribute__((ext_vector_type(8))) short short8;
typedef __attribute__((ext_vector_type(4))) float floatx4;

static __device__ __forceinline__ uint16_t f2bf(float f) {
  uint32_t u = __builtin_bit_cast(uint32_t, f);
  u = (u + 0x7FFFu + ((u >> 16) & 1u)) >> 16;
  return (uint16_t)u;
}
static __device__ __forceinline__ float bf2f(uint16_t h) {
  uint32_t u = ((uint32_t)h) << 16;
  return __builtin_bit_cast(float, u);
}
static __device__ __forceinline__ uint16_t f2h(float f) {
  _Float16 h = (_Float16)f;
  return __builtin_bit_cast(uint16_t, h);
}
static __device__ __forceinline__ float h2f(uint16_t u) {
  return (float)__builtin_bit_cast(_Float16, u);
}
static __device__ __forceinline__ float swishf(float z) {
  return z * __builtin_amdgcn_rcpf(1.f + __expf(-z));
}
// load 8 fp16 attn values for (b,n,m): 4 from each head-plane
static __device__ __forceinline__ void ld_attn8(const uint16_t* __restrict__ attn,
                                                size_t off, float* a) {
  uint2 v0 = *(const uint2*)(attn + off);
  uint2 v1 = *(const uint2*)(attn + PLH_ + off);
  a[0] = h2f((uint16_t)(v0.x & 0xFFFFu)); a[1] = h2f((uint16_t)(v0.x >> 16));
  a[2] = h2f((uint16_t)(v0.y & 0xFFFFu)); a[3] = h2f((uint16_t)(v0.y >> 16));
  a[4] = h2f((uint16_t)(v1.x & 0xFFFFu)); a[5] = h2f((uint16_t)(v1.x >> 16));
  a[6] = h2f((uint16_t)(v1.y & 0xFFFFu)); a[7] = h2f((uint16_t)(v1.y >> 16));
}

// gn1 affine (al,be) for group g's 8 channels from per-batch moments
static __device__ __forceinline__ void gn1_affine(const float* __restrict__ moms,
    const float* __restrict__ ew, const float* __restrict__ gs,
    const float* __restrict__ gb, int b, int g, float* al, float* be) {
  float m1[8];
#pragma unroll
  for (int h = 0; h < 8; ++h) m1[h] = moms[b * 44 + h];
  float sum = 0.f, ssq = 0.f;
#pragma unroll
  for (int o2 = 0; o2 < 8; ++o2) {
    int o = g * 8 + o2;
    float e[8];
#pragma unroll
    for (int h = 0; h < 8; ++h) e[h] = ew[o * 8 + h];
    float so = 0.f;
#pragma unroll
    for (int h = 0; h < 8; ++h) so += e[h] * m1[h];
    sum += so;
    int idx = 8;
#pragma unroll
    for (int h = 0; h < 8; ++h)
#pragma unroll
      for (int h2 = h; h2 < 8; ++h2) {
        float cf = e[h] * e[h2] * ((h == h2) ? 1.f : 2.f);
        ssq += cf * moms[b * 44 + idx];
        ++idx;
      }
  }
  float mean = sum * (1.f / CNT_);
  float var = ssq * (1.f / CNT_) - mean * mean;
  float inv = rsqrtf(var + EPS_);
#pragma unroll
  for (int o2 = 0; o2 < 8; ++o2) {
    al[o2] = inv * gs[g * 8 + o2];
    be[o2] = gb[g * 8 + o2] - mean * al[o2];
  }
}

// ---------------------------------------------------------------------------
// 1) kvxbf[b][m][c] (bf16) = depthwise 8x8/stride-8 downsample; also xbf
// ---------------------------------------------------------------------------
__global__ __launch_bounds__(256) void k_kvx(const float* __restrict__ x,
                                             const float* __restrict__ dw,
                                             uint16_t* __restrict__ kvxbf,
                                             uint16_t* __restrict__ xbf) {
  int g = blockIdx.x * 256 + threadIdx.x;
  int b = g / (C_ * NK_);
  int rem = g % (C_ * NK_);
  int c = rem / NK_;
  int m = rem % NK_;
  int ph = m / 7, pw = m % 7;
  const size_t base = ((size_t)(b * C_ + c)) * N_ + (ph * 8) * HIMG + pw * 8;
  const float* xp = x + base;
  uint16_t* xbp = xbf + base;
  const float* wp = dw + c * 64;
  float acc = 0.f;
#pragma unroll
  for (int i = 0; i < 8; ++i) {
    float4 a  = *(const float4*)(xp + i * HIMG);
    float4 bq = *(const float4*)(xp + i * HIMG + 4);
    acc += a.x*wp[i*8+0] + a.y*wp[i*8+1] + a.z*wp[i*8+2] + a.w*wp[i*8+3]
         + bq.x*wp[i*8+4] + bq.y*wp[i*8+5] + bq.z*wp[i*8+6] + bq.w*wp[i*8+7];
    uint32_t q0 = (uint32_t)f2bf(a.x)  | ((uint32_t)f2bf(a.y)  << 16);
    uint32_t q1 = (uint32_t)f2bf(a.z)  | ((uint32_t)f2bf(a.w)  << 16);
    uint32_t q2 = (uint32_t)f2bf(bq.x) | ((uint32_t)f2bf(bq.y) << 16);
    uint32_t q3 = (uint32_t)f2bf(bq.z) | ((uint32_t)f2bf(bq.w) << 16);
    *(uint4*)(xbp + (size_t)i * HIMG) = make_uint4(q0, q1, q2, q3);
  }
  kvxbf[((size_t)(b * NK_ + m)) * C_ + c] = f2bf(acc);
}

// ---------------------------------------------------------------------------
// 2) kv[b][m][col] = sum_c kvx[b][m][c] * kv_w[c][col]  -- MFMA bf16
// ---------------------------------------------------------------------------
__global__ __launch_bounds__(256) void k_kv(const uint16_t* __restrict__ kvxbf,
                                            const float* __restrict__ kv_w,
                                            float* __restrict__ kv) {
  const int ct = blockIdx.x, b = blockIdx.y;
  const int j0 = ct * 64;
  const int tid = threadIdx.x, wvid = tid >> 6, lane = tid & 63;
  __shared__ __align__(16) uint32_t A32[64 * 20];
  __shared__ __align__(16) uint32_t B32[64 * 20];
  floatx4 acc[4];
#pragma unroll
  for (int t = 0; t < 4; ++t) acc[t] = (floatx4){0.f,0.f,0.f,0.f};
  const int am = tid & 63, ak = tid >> 6;
  const int bj = tid & 63, bk = tid >> 6;
  for (int ks = 0; ks < 16; ++ks) {
    const int c0 = ks * 32;
    __syncthreads();
    {
      uint4 av = make_uint4(0, 0, 0, 0);
      if (am < NK_)
        av = *(const uint4*)(kvxbf + ((size_t)(b * NK_ + am)) * C_ + c0 + ak * 8);
      *(uint4*)&A32[am * 20 + ak * 4] = av;
    }
    {
      uint32_t pk[4];
#pragma unroll
      for (int r = 0; r < 4; ++r) {
        float f0 = kv_w[(size_t)(c0 + bk * 8 + 2 * r)     * 1024 + j0 + bj];
        float f1 = kv_w[(size_t)(c0 + bk * 8 + 2 * r + 1) * 1024 + j0 + bj];
        pk[r] = (uint32_t)f2bf(f0) | ((uint32_t)f2bf(f1) << 16);
      }
      *(uint4*)&B32[bj * 20 + bk * 4] = make_uint4(pk[0], pk[1], pk[2], pk[3]);
    }
    __syncthreads();
    short8 af = *(const short8*)&A32[(wvid * 16 + (lane & 15)) * 20 + (lane >> 4) * 4];
#pragma unroll
    for (int t = 0; t < 4; ++t) {
      short8 bfb = *(const short8*)&B32[(t * 16 + (lane & 15)) * 20 + (lane >> 4) * 4];
      acc[t] = __builtin_amdgcn_mfma_f32_16x16x32_bf16(af, bfb, acc[t], 0, 0, 0);
    }
  }
  const int rb = wvid * 16 + ((lane >> 4) << 2), cb = lane & 15;
#pragma unroll
  for (int t = 0; t < 4; ++t)
#pragma unroll
    for (int r2 = 0; r2 < 4; ++r2) {
      int m = rb + r2;
      if (m < NK_)
        kv[((size_t)(b * NK_ + m)) * 1024 + j0 + t * 16 + cb] = acc[t][r2];
    }
}

// ---------------------------------------------------------------------------
// 3+4 merged) z=0: wqkT[b][h*52+m][c] = SCALE*sum_d q_w[c][h*64+d]*k[b][h][m][d]
//             z=1: wvT[b][c'][h*52+m] = sum_d v[b][h][m][d]*proj_w[h*64+d][c']
// ---------------------------------------------------------------------------
__global__ __launch_bounds__(256) void k_wqkv(const float* __restrict__ kv,
                                              const float* __restrict__ q_w,
                                              const float* __restrict__ proj_w,
                                              uint16_t* __restrict__ wqkT,
                                              uint16_t* __restrict__ wvT) {
  int b = blockIdx.x, h = blockIdx.y;
  __shared__ float sm[56 * 64];
  if (blockIdx.z == 0) {
    for (int idx = threadIdx.x; idx < 56 * 64; idx += 256) {
      int m = idx >> 6, d = idx & 63;
      sm[idx] = (m < NK_) ? kv[((size_t)(b * NK_ + m)) * 1024 + h * HD_ + d] : 0.f;
    }
    __syncthreads();
#pragma unroll
    for (int cc = 0; cc < 2; ++cc) {
      int c = threadIdx.x + cc * 256;
      float qrow[64];
      const float* qp = q_w + (size_t)c * C_ + h * HD_;
#pragma unroll
      for (int d = 0; d < 64; ++d) qrow[d] = qp[d];
      for (int mc = 0; mc < NK_; mc += 8) {
        int cnt = min(8, NK_ - mc);
        float acc[8] = {0,0,0,0,0,0,0,0};
        for (int d = 0; d < 64; ++d) {
          float q = qrow[d];
#pragma unroll
          for (int i = 0; i < 8; ++i) acc[i] += q * sm[(mc + i) * 64 + d];
        }
        for (int i = 0; i < cnt; ++i)
          wqkT[((size_t)(b * J_ + h * JP_ + mc + i)) * C_ + c] = f2bf(acc[i] * SCALE_);
      }
    }
    for (int idx = threadIdx.x; idx < 3 * C_; idx += 256) {
      int rr = idx / C_, c = idx % C_;
      wqkT[((size_t)(b * J_ + h * JP_ + 49 + rr)) * C_ + c] = 0;
    }
  } else {
    for (int idx = threadIdx.x; idx < 56 * 64; idx += 256) {
      int m = idx >> 6, d = idx & 63;
      sm[idx] = (m < NK_) ? kv[((size_t)(b * NK_ + m)) * 1024 + 512 + h * HD_ + d] : 0.f;
    }
    __syncthreads();
#pragma unroll
    for (int cc = 0; cc < 2; ++cc) {
      int c = threadIdx.x + cc * 256;
      for (int mc = 0; mc < NK_; mc += 8) {
        int cnt = min(8, NK_ - mc);
        float acc[8] = {0,0,0,0,0,0,0,0};
        for (int d = 0; d < 64; ++d) {
          float w = proj_w[(size_t)(h * HD_ + d) * C_ + c];
#pragma unroll
          for (int i = 0; i < 8; ++i) acc[i] += sm[(mc + i) * 64 + d] * w;
        }
        uint16_t* dst = wvT + ((size_t)(b * C_ + c)) * J_ + h * JP_ + mc;
        if (cnt == 8) {
          uint32_t pk[4];
#pragma unroll
          for (int i = 0; i < 4; ++i)
            pk[i] = (uint32_t)f2bf(acc[2*i]) | ((uint32_t)f2bf(acc[2*i+1]) << 16);
          *(uint2*)(dst)     = make_uint2(pk[0], pk[1]);
          *(uint2*)(dst + 4) = make_uint2(pk[2], pk[3]);
        } else {
          for (int i = 0; i < cnt; ++i) dst[i] = f2bf(acc[i]);
        }
      }
      uint16_t* pd = wvT + ((size_t)(b * C_ + c)) * J_ + h * JP_ + 49;
      pd[0] = 0; pd[1] = 0; pd[2] = 0;
    }
  }
}

// ---------------------------------------------------------------------------
// 5) GEMM1 + softmax (R7 core; Ss stride 213 kills the 8-way bank conflict
//    in the scalar softmax/epilogue phases). fp16 two-plane output.
// ---------------------------------------------------------------------------
__global__ __launch_bounds__(256) void k_attn(const uint16_t* __restrict__ xbf,
                                              const uint16_t* __restrict__ wqkT,
                                              const float* __restrict__ rel_bias,
                                              uint16_t* __restrict__ attn) {
  const int mt = blockIdx.x, ct = blockIdx.y, b = blockIdx.z;
  const int n0 = mt * 64, j0 = ct * 208;
  const int tid = threadIdx.x, wvid = tid >> 6, lane = tid & 63;
  __shared__ __align__(16) char smem[64 * SST_ * 4];  // 54528 B
  uint32_t* A32 = (uint32_t*)smem;          // [64][20]
  uint32_t* B32 = A32 + 64 * 20;            // [208][20]
  float* Ss = (float*)smem;                 // [64][213] epilogue (aliases stage)

  floatx4 acc[13];
#pragma unroll
  for (int t = 0; t < 13; ++t) acc[t] = (floatx4){0.f,0.f,0.f,0.f};

  const int an = tid & 63, acp = tid >> 6;
  for (int ks = 0; ks < 16; ++ks) {
    const int c0 = ks * 32;
    __syncthreads();
    {
      const uint16_t* xb = xbf + ((size_t)(b * C_ + c0 + acp * 8)) * N_ + n0 + an;
      uint32_t pk[4];
#pragma unroll
      for (int jj = 0; jj < 4; ++jj) {
        uint32_t f0 = xb[(size_t)(2*jj) * N_];
        uint32_t f1 = xb[(size_t)(2*jj+1) * N_];
        pk[jj] = f0 | (f1 << 16);
      }
      *(uint4*)&A32[an * 20 + acp * 4] = make_uint4(pk[0], pk[1], pk[2], pk[3]);
    }
    for (int idx = tid; idx < 832; idx += 256) {
      int jl = idx >> 2, q = idx & 3;
      uint4 v = *(const uint4*)(wqkT + ((size_t)b * J_ + j0 + jl) * C_ + c0 + q * 8);
      *(uint4*)&B32[jl * 20 + q * 4] = v;
    }
    __syncthreads();
    short8 af = *(const short8*)&A32[(wvid * 16 + (lane & 15)) * 20 + (lane >> 4) * 4];
#pragma unroll
    for (int t = 0; t < 13; ++t) {
      short8 bfb = *(const short8*)&B32[(16 * t + (lane & 15)) * 20 + (lane >> 4) * 4];
      acc[t] = __builtin_amdgcn_mfma_f32_16x16x32_bf16(af, bfb, acc[t], 0, 0, 0);
    }
  }
  __syncthreads();
  {
    const int rb = wvid * 16 + ((lane >> 4) << 2), cb = lane & 15;
#pragma unroll
    for (int t = 0; t < 13; ++t)
#pragma unroll
      for (int r2 = 0; r2 < 4; ++r2)
        Ss[(rb + r2) * SST_ + t * 16 + cb] = acc[t][r2];
  }
  __syncthreads();
  {
    const int row = tid >> 2, hh = tid & 3;
    const int n = n0 + row;
    const float* bias = rel_bias + (size_t)n * NK_;
    float* srow = &Ss[row * SST_ + hh * JP_];
    float mx = -1e30f;
    for (int m = 0; m < NK_; ++m) mx = fmaxf(mx, srow[m] + bias[m]);
    float sum = 0.f;
    for (int m = 0; m < NK_; ++m) { float e = __expf(srow[m] + bias[m] - mx); srow[m] = e; sum += e; }
    float inv = 1.f / sum;
    for (int m = 0; m < NK_; ++m) srow[m] *= inv;
  }
  __syncthreads();
  // coalesced write: plane ct, [b][n][49][4] fp16
  uint16_t* dst = attn + (size_t)ct * PLH_ + ((size_t)b * N_ + n0) * NK_ * 4;
  for (int task = tid; task < 64 * NK_; task += 256) {
    int row = task / NK_, m = task % NK_;
    const float* sr = &Ss[row * SST_];
    uint32_t lo = (uint32_t)f2h(sr[m])         | ((uint32_t)f2h(sr[JP_ + m])   << 16);
    uint32_t hi = (uint32_t)f2h(sr[2*JP_ + m]) | ((uint32_t)f2h(sr[3*JP_ + m]) << 16);
    *(uint2*)(dst + (size_t)task * 4) = make_uint2(lo, hi);
  }
}

// ---------------------------------------------------------------------------
// 6) attn moments per batch (fp16 attn, two planes)
// ---------------------------------------------------------------------------
__global__ __launch_bounds__(256) void k_moms(const uint16_t* __restrict__ attn,
                                              float* __restrict__ moms) {
  int nt = blockIdx.x, b = blockIdx.y;
  float vals[44];
#pragma unroll
  for (int k = 0; k < 44; ++k) vals[k] = 0.f;
  for (int task = threadIdx.x; task < 64 * NK_; task += 256) {
    float a[8];
    ld_attn8(attn, ((size_t)b * N_ + nt * 64) * NK_ * 4 + (size_t)task * 4, a);
#pragma unroll
    for (int h = 0; h < 8; ++h) vals[h] += a[h];
    int idx = 8;
#pragma unroll
    for (int h = 0; h < 8; ++h)
#pragma unroll
      for (int h2 = h; h2 < 8; ++h2) { vals[idx] += a[h] * a[h2]; ++idx; }
  }
  __shared__ float red[4][44];
  int lane = threadIdx.x & 63, wvid = threadIdx.x >> 6;
#pragma unroll
  for (int k = 0; k < 44; ++k) {
#pragma unroll
    for (int off = 32; off; off >>= 1) vals[k] += __shfl_down(vals[k], off, 64);
  }
  if (lane == 0) {
#pragma unroll
    for (int k = 0; k < 44; ++k) red[wvid][k] = vals[k];
  }
  __syncthreads();
  if (threadIdx.x < 44) {
    float t = red[0][threadIdx.x] + red[1][threadIdx.x] + red[2][threadIdx.x] + red[3][threadIdx.x];
    atomicAdd(&moms[b * 44 + threadIdx.x], t);
  }
}

// ---------------------------------------------------------------------------
// 6b) gn1 affine precompute
// ---------------------------------------------------------------------------
__global__ void k_aff(const float* __restrict__ moms, const float* __restrict__ ew,
                      const float* __restrict__ gn1_s, const float* __restrict__ gn1_b,
                      float* __restrict__ gn1ab) {
  int t = threadIdx.x;
  if (t >= 48) return;
  int b = t / 3, g = t % 3;
  float al[8], be[8];
  gn1_affine(moms, ew, gn1_s, gn1_b, b, g, al, be);
#pragma unroll
  for (int o = 0; o < 8; ++o) { gn1ab[t * 16 + o] = al[o]; gn1ab[t * 16 + 8 + o] = be[o]; }
}

// ---------------------------------------------------------------------------
// 6c) gn2 affine precompute (after k_dla0)
// ---------------------------------------------------------------------------
__global__ void k_aff2(const float* __restrict__ gn2sums, const float* __restrict__ gn2_s,
                       const float* __restrict__ gn2_b, float* __restrict__ gn2ab) {
  int t = threadIdx.x;
  if (t >= 48) return;
  int b = t / 3, g = t % 3;
  float s2 = gn2sums[b * 6 + g * 2], q2 = gn2sums[b * 6 + g * 2 + 1];
  float mean = s2 * (1.f / CNT_);
  float var = q2 * (1.f / CNT_) - mean * mean;
  float inv = rsqrtf(var + EPS_);
#pragma unroll
  for (int o = 0; o < 8; ++o) {
    float al = inv * gn2_s[g * 8 + o];
    gn2ab[t * 16 + o] = al;
    gn2ab[t * 16 + 8 + o] = gn2_b[g * 8 + o] - mean * al;
  }
}

// ---------------------------------------------------------------------------
// 7a) DLA pass 0 (R7 per-group form): h1 -> LDS, 3x3 stencil -> a2;
//     gn2 sums; opt. store a2 fp16
// ---------------------------------------------------------------------------
template<bool STORE>
__global__ __launch_bounds__(256) void k_dla0_t(const uint16_t* __restrict__ attn,
    const float* __restrict__ ew, const float* __restrict__ gn1ab,
    const float* __restrict__ dww, float* __restrict__ gn2sums,
    uint16_t* __restrict__ a2buf) {
  const int nt = blockIdx.x, b = blockIdx.y, g = blockIdx.z;  // 196 x 16 x 3
  const int n0 = nt * 16;
  __shared__ __align__(16) float h1s[18 * 51 * 8];   // 29376 B
  __shared__ float red[4][2];
  float al[8], be[8];
  {
    const float* ab = gn1ab + (b * 3 + g) * 16;
#pragma unroll
    for (int o = 0; o < 8; ++o) { al[o] = ab[o]; be[o] = ab[8 + o]; }
  }
  for (int task = threadIdx.x; task < 18 * NK_; task += 256) {
    int r = task / NK_, m = task % NK_;
    int n = n0 - 1 + r;
    float h1v[8];
    if (n < 0 || n >= N_) {
#pragma unroll
      for (int o = 0; o < 8; ++o) h1v[o] = 0.f;
    } else {
      float a[8];
      ld_attn8(attn, (((size_t)b * N_ + n) * NK_ + m) * 4, a);
#pragma unroll
      for (int o = 0; o < 8; ++o) {
        float v = 0.f;
#pragma unroll
        for (int h = 0; h < 8; ++h) v += ew[(g * 8 + o) * 8 + h] * a[h];
        h1v[o] = swishf(v * al[o] + be[o]);
      }
    }
    float* dst = &h1s[(r * 51 + m + 1) * 8];
    *(float4*)dst = make_float4(h1v[0], h1v[1], h1v[2], h1v[3]);
    *(float4*)(dst + 4) = make_float4(h1v[4], h1v[5], h1v[6], h1v[7]);
  }
  for (int idx = threadIdx.x; idx < 18 * 16; idx += 256) {
    int r = idx >> 4, c = idx & 15;
    h1s[(r * 51 + (c >> 3) * 50) * 8 + (c & 7)] = 0.f;
  }
  __syncthreads();
  const int row = threadIdx.x >> 4, mg = threadIdx.x & 15;
  const int m0 = mg * 3;
  const int mlim = (mg == 15) ? 4 : 3;
  float a2[4][8];
#pragma unroll
  for (int mi = 0; mi < 4; ++mi)
#pragma unroll
    for (int o = 0; o < 8; ++o) a2[mi][o] = 0.f;
#pragma unroll
  for (int dr = 0; dr < 3; ++dr) {
    float win[48];
    const float* src = &h1s[((row + dr) * 51 + m0) * 8];
#pragma unroll
    for (int k = 0; k < 12; ++k)
      *(float4*)&win[k * 4] = *(const float4*)(src + k * 4);
#pragma unroll
    for (int o = 0; o < 8; ++o) {
      float wa = dww[(g * 8 + o) * 9 + dr * 3 + 0];
      float wb = dww[(g * 8 + o) * 9 + dr * 3 + 1];
      float wc = dww[(g * 8 + o) * 9 + dr * 3 + 2];
#pragma unroll
      for (int mi = 0; mi < 4; ++mi)
        a2[mi][o] += win[mi * 8 + o] * wa + win[(mi + 1) * 8 + o] * wb + win[(mi + 2) * 8 + o] * wc;
    }
  }
  float s0 = 0.f, q0 = 0.f;
#pragma unroll
  for (int mi = 0; mi < 4; ++mi) {
    if (mi < mlim) {
#pragma unroll
      for (int o = 0; o < 8; ++o) { s0 += a2[mi][o]; q0 += a2[mi][o] * a2[mi][o]; }
    }
  }
  int lane = threadIdx.x & 63, wvid = threadIdx.x >> 6;
#pragma unroll
  for (int off = 32; off; off >>= 1) { s0 += __shfl_down(s0, off, 64); q0 += __shfl_down(q0, off, 64); }
  if (lane == 0) { red[wvid][0] = s0; red[wvid][1] = q0; }
  __syncthreads();
  if (threadIdx.x < 2) {
    float t = red[0][threadIdx.x] + red[1][threadIdx.x] + red[2][threadIdx.x] + red[3][threadIdx.x];
    atomicAdd(&gn2sums[b * 6 + g * 2 + threadIdx.x], t);
  }
  if (STORE) {
    uint32_t* a2s = (uint32_t*)h1s;
#pragma unroll
    for (int mi = 0; mi < 4; ++mi) {
      if (mi < mlim) {
        uint32_t pk[4];
#pragma unroll
        for (int q = 0; q < 4; ++q)
          pk[q] = (uint32_t)f2h(a2[mi][2*q]) | ((uint32_t)f2h(a2[mi][2*q+1]) << 16);
        *(uint4*)&a2s[(row * NK_ + m0 + mi) * 4] = make_uint4(pk[0], pk[1], pk[2], pk[3]);
      }
    }
    __syncthreads();
    uint16_t* dstb = a2buf + ((size_t)(b * 3 + g) * POS_ + (size_t)n0 * NK_) * 8;
    for (int idx = threadIdx.x; idx < 16 * NK_; idx += 256)
      *(uint4*)(dstb + (size_t)idx * 8) = *(const uint4*)&a2s[idx * 4];
  }
}

// ---------------------------------------------------------------------------
// 7b-BIG) elementwise: a2 fp16 -> gn2 affine+swish -> 24->8 reduce -> rbuf
// ---------------------------------------------------------------------------
__global__ __launch_bounds__(256) void k_dla1b(const uint16_t* __restrict__ a2buf,
    const float* __restrict__ gn2ab, const float* __restrict__ rww,
    float* __restrict__ gn3sums, uint16_t* __restrict__ rbuf) {
  const int b = blockIdx.y;
  const int pos = blockIdx.x * 256 + threadIdx.x;
  __shared__ float rws[192];
  __shared__ float red[4][2];
  for (int i = threadIdx.x; i < 192; i += 256) rws[i] = rww[i];
  __syncthreads();
  float r[8] = {0.f,0.f,0.f,0.f,0.f,0.f,0.f,0.f};
  if (pos < POS_) {
#pragma unroll
    for (int g = 0; g < 3; ++g) {
      const float* ab = gn2ab + (b * 3 + g) * 16;
      uint4 v = *(const uint4*)(a2buf + ((size_t)(b * 3 + g) * POS_ + pos) * 8);
      uint32_t w[4] = {v.x, v.y, v.z, v.w};
#pragma unroll
      for (int q = 0; q < 4; ++q) {
#pragma unroll
        for (int hl = 0; hl < 2; ++hl) {
          int o = q * 2 + hl;
          float f = h2f((uint16_t)(hl ? (w[q] >> 16) : (w[q] & 0xFFFFu)));
          float sw = swishf(f * ab[o] + ab[8 + o]);
#pragma unroll
          for (int p = 0; p < 8; ++p) r[p] += rws[p * HID_ + g * 8 + o] * sw;
        }
      }
    }
  }
  float sr = 0.f, qr = 0.f;
#pragma unroll
  for (int p = 0; p < 8; ++p) { sr += r[p]; qr += r[p] * r[p]; }
  int lane = threadIdx.x & 63, wvid = threadIdx.x >> 6;
#pragma unroll
  for (int off = 32; off; off >>= 1) { sr += __shfl_down(sr, off, 64); qr += __shfl_down(qr, off, 64); }
  if (lane == 0) { red[wvid][0] = sr; red[wvid][1] = qr; }
  __syncthreads();
  if (threadIdx.x < 2) {
    float t = red[0][threadIdx.x] + red[1][threadIdx.x] + red[2][threadIdx.x] + red[3][threadIdx.x];
    atomicAdd(&gn3sums[b * 2 + threadIdx.x], t);
  }
  if (pos < POS_) {
    int n = pos / NK_, m = pos - n * NK_;
    uint16_t* dst = rbuf + ((size_t)b * N_ + n) * J_;
#pragma unroll
    for (int p = 0; p < 8; ++p) dst[p * JP_ + m] = f2bf(r[p]);
    if (m < 3) {
#pragma unroll
      for (int p = 0; p < 8; ++p) dst[p * JP_ + 49 + m] = 0;
    }
  }
}

// ---------------------------------------------------------------------------
// 7b-SMALL) fallback: recompute path (fp16 attn planes), precomputed affines
// ---------------------------------------------------------------------------
__global__ __launch_bounds__(256) void k_dla1s(const uint16_t* __restrict__ attn,
    const float* __restrict__ ew, const float* __restrict__ gn1ab,
    const float* __restrict__ dww, const float* __restrict__ gn2ab,
    const float* __restrict__ rww, float* __restrict__ gn3sums,
    uint16_t* __restrict__ rbuf) {
  const int nt = blockIdx.x, b = blockIdx.y;
  const int n0 = nt * 16;
  __shared__ __align__(16) float h1s[18 * 51 * 8];
  __shared__ float red[4][2];
  const int row = threadIdx.x >> 4, mg = threadIdx.x & 15;
  const int m0 = mg * 3;
  const int mlim = (mg == 15) ? 4 : 3;
  float racc[4][8];
#pragma unroll
  for (int mi = 0; mi < 4; ++mi)
#pragma unroll
    for (int p = 0; p < 8; ++p) racc[mi][p] = 0.f;

  for (int g = 0; g < 3; ++g) {
    float al[8], be[8], al2[8], be2[8];
    {
      const float* ab1 = gn1ab + (b * 3 + g) * 16;
      const float* ab2 = gn2ab + (b * 3 + g) * 16;
#pragma unroll
      for (int o = 0; o < 8; ++o) {
        al[o] = ab1[o]; be[o] = ab1[8 + o];
        al2[o] = ab2[o]; be2[o] = ab2[8 + o];
      }
    }
    __syncthreads();
    for (int task = threadIdx.x; task < 18 * NK_; task += 256) {
      int r = task / NK_, m = task % NK_;
      int n = n0 - 1 + r;
      float h1v[8];
      if (n < 0 || n >= N_) {
#pragma unroll
        for (int o = 0; o < 8; ++o) h1v[o] = 0.f;
      } else {
        float a[8];
        ld_attn8(attn, (((size_t)b * N_ + n) * NK_ + m) * 4, a);
#pragma unroll
        for (int o = 0; o < 8; ++o) {
          float v = 0.f;
#pragma unroll
          for (int h = 0; h < 8; ++h) v += ew[(g * 8 + o) * 8 + h] * a[h];
          h1v[o] = swishf(v * al[o] + be[o]);
        }
      }
      float* dst = &h1s[(r * 51 + m + 1) * 8];
      *(float4*)dst = make_float4(h1v[0], h1v[1], h1v[2], h1v[3]);
      *(float4*)(dst + 4) = make_float4(h1v[4], h1v[5], h1v[6], h1v[7]);
    }
    for (int idx = threadIdx.x; idx < 18 * 16; idx += 256) {
      int r = idx >> 4, c = idx & 15;
      h1s[(r * 51 + (c >> 3) * 50) * 8 + (c & 7)] = 0.f;
    }
    __syncthreads();
    float a2[4][8];
#pragma unroll
    for (int mi = 0; mi < 4; ++mi)
#pragma unroll
      for (int o = 0; o < 8; ++o) a2[mi][o] = 0.f;
#pragma unroll
    for (int dr = 0; dr < 3; ++dr) {
      float win[48];
      const float* src = &h1s[((row + dr) * 51 + m0) * 8];
#pragma unroll
      for (int k = 0; k < 12; ++k)
        *(float4*)&win[k * 4] = *(const float4*)(src + k * 4);
#pragma unroll
      for (int o = 0; o < 8; ++o) {
        float wa = dww[(g * 8 + o) * 9 + dr * 3 + 0];
        float wb = dww[(g * 8 + o) * 9 + dr * 3 + 1];
        float wc = dww[(g * 8 + o) * 9 + dr * 3 + 2];
#pragma unroll
        for (int mi = 0; mi < 4; ++mi)
          a2[mi][o] += win[mi * 8 + o] * wa + win[(mi + 1) * 8 + o] * wb + win[(mi + 2) * 8 + o] * wc;
      }
    }
#pragma unroll
    for (int mi = 0; mi < 4; ++mi) {
      if (mi < mlim) {
#pragma unroll
        for (int o = 0; o < 8; ++o) {
          float sw = swishf(a2[mi][o] * al2[o] + be2[o]);
#pragma unroll
          for (int p = 0; p < 8; ++p) racc[mi][p] += rww[p * HID_ + g * 8 + o] * sw;
        }
      }
    }
  }
  float sr = 0.f, qr = 0.f;
  const int n = n0 + row;
  uint16_t* dstbase = rbuf + ((size_t)b * N_ + n) * J_;
#pragma unroll
  for (int mi = 0; mi < 4; ++mi) {
    if (mi < mlim) {
      int m = m0 + mi;
#pragma unroll
      for (int p = 0; p < 8; ++p) {
        float v = racc[mi][p];
        dstbase[p * JP_ + m] = f2bf(v);
        sr += v; qr += v * v;
      }
    }
  }
  if (mg == 15) {
#pragma unroll
    for (int p = 0; p < 8; ++p) {
      dstbase[p * JP_ + 49] = 0; dstbase[p * JP_ + 50] = 0; dstbase[p * JP_ + 51] = 0;
    }
  }
  int lane = threadIdx.x & 63, wvid = threadIdx.x >> 6;
#pragma unroll
  for (int off = 32; off; off >>= 1) { sr += __shfl_down(sr, off, 64); qr += __shfl_down(qr, off, 64); }
  if (lane == 0) { red[wvid][0] = sr; red[wvid][1] = qr; }
  __syncthreads();
  if (threadIdx.x < 2) {
    float t = red[0][threadIdx.x] + red[1][threadIdx.x] + red[2][threadIdx.x] + red[3][threadIdx.x];
    atomicAdd(&gn3sums[b * 2 + threadIdx.x], t);
  }
}

// ---------------------------------------------------------------------------
// 8) GEMM2: out[b][n][c'] = sum_j gn3(r)[n][j] * wvT[b][c'][j] + proj_b[c']
// ---------------------------------------------------------------------------
__global__ __launch_bounds__(256) void k_out(const uint16_t* __restrict__ rr,
    const uint16_t* __restrict__ wvT, const float* __restrict__ gn3sums,
    const float* __restrict__ gn3_s, const float* __restrict__ gn3_b,
    const float* __restrict__ proj_b, float* __restrict__ outp) {
  const int mt = blockIdx.x, ct = blockIdx.y, b = blockIdx.z;
  const int n0 = mt * 64, c0 = ct * 128;
  const int tid = threadIdx.x, wvid = tid >> 6, lane = tid & 63;
  __shared__ __align__(16) uint32_t A32[64 * 20];
  __shared__ __align__(16) uint32_t B32[128 * 20];
  __shared__ float ab3[J_ * 2];
  {
    float ssum = gn3sums[b*2], sq = gn3sums[b*2+1];
    float mean = ssum * (1.f / CNT_);
    float var = sq * (1.f / CNT_) - mean * mean;
    float inv = rsqrtf(var + EPS_);
    for (int j = tid; j < J_; j += 256) {
      int h = j / JP_;
      float al = inv * gn3_s[h];
      ab3[j*2] = al; ab3[j*2+1] = gn3_b[h] - mean * al;
    }
  }
  floatx4 acc[8];
#pragma unroll
  for (int t = 0; t < 8; ++t) acc[t] = (floatx4){0.f,0.f,0.f,0.f};
  const int an = tid >> 2, acp = tid & 3;
  for (int ks = 0; ks < 13; ++ks) {
    const int k0 = ks * 32;
    __syncthreads();
    {
      const uint16_t* src = rr + ((size_t)b * N_ + n0 + an) * J_ + k0 + acp * 8;
      uint4 v = *(const uint4*)src;
      uint32_t raw[4] = {v.x, v.y, v.z, v.w};
      uint32_t pk[4];
#pragma unroll
      for (int jj = 0; jj < 4; ++jj) {
        int j = k0 + acp * 8 + jj * 2;
        float f0 = bf2f((uint16_t)(raw[jj] & 0xFFFFu)) * ab3[j*2]     + ab3[j*2+1];
        float f1 = bf2f((uint16_t)(raw[jj] >> 16))     * ab3[(j+1)*2] + ab3[(j+1)*2+1];
        pk[jj] = (uint32_t)f2bf(f0) | ((uint32_t)f2bf(f1) << 16);
      }
      *(uint4*)&A32[an * 20 + acp * 4] = make_uint4(pk[0], pk[1], pk[2], pk[3]);
    }
    for (int idx = tid; idx < 128 * 4; idx += 256) {
      int rw2 = idx >> 2, q = idx & 3;
      uint4 v = *(const uint4*)(wvT + ((size_t)b * C_ + c0 + rw2) * J_ + k0 + q * 8);
      *(uint4*)&B32[rw2 * 20 + q * 4] = v;
    }
    __syncthreads();
    short8 af = *(const short8*)&A32[(wvid * 16 + (lane & 15)) * 20 + (lane >> 4) * 4];
#pragma unroll
    for (int t = 0; t < 8; ++t) {
      short8 bfb = *(const short8*)&B32[(t * 16 + (lane & 15)) * 20 + (lane >> 4) * 4];
      acc[t] = __builtin_amdgcn_mfma_f32_16x16x32_bf16(af, bfb, acc[t], 0, 0, 0);
    }
  }
  const int rb = wvid * 16 + ((lane >> 4) << 2);
#pragma unroll
  for (int t = 0; t < 8; ++t) {
    int c = c0 + t * 16 + (lane & 15);
    float pb = proj_b[c];
#pragma unroll
    for (int r2 = 0; r2 < 4; ++r2)
      outp[((size_t)b * N_ + n0 + rb + r2) * C_ + c] = acc[t][r2] + pb;
  }
}

// ---------------------------------------------------------------------------
extern "C" void kernel_launch(void* const* d_in, const int* in_sizes, int n_in,
                              void* d_out, int out_size, void* d_ws, size_t ws_size,
                              hipStream_t stream) {
  (void)in_sizes; (void)n_in; (void)out_size;
  const float* x      = (const float*)d_in[0];
  const float* q_w    = (const float*)d_in[1];
  const float* down_w = (const float*)d_in[2];
  const float* kv_w   = (const float*)d_in[3];
  const float* proj_w = (const float*)d_in[4];
  const float* proj_b = (const float*)d_in[5];
  const float* rel_b  = (const float*)d_in[6];
  const float* ew     = (const float*)d_in[7];
  const float* gn1_s  = (const float*)d_in[8];
  const float* gn1_b  = (const float*)d_in[9];
  const float* dw_w   = (const float*)d_in[10];
  const float* gn2_s  = (const float*)d_in[11];
  const float* gn2_b  = (const float*)d_in[12];
  const float* red_w  = (const float*)d_in[13];
  const float* gn3_s  = (const float*)d_in[14];
  const float* gn3_b  = (const float*)d_in[15];
  float* outp = (float*)d_out;

  // Early region (both paths): xbf@0 (51,380,224); kvxbf@51,380,224 (802,816);
  //   kv@52,183,040 (3,211,264); wqkT@55,394,304 (8,388,608 slot) -> 63,782,912
  // BIG: a2@0 (118,013,952, overlaps dead early region);
  //   attn@118,013,952 (39,337,984 two planes); wvT@157,351,936 (6,815,744);
  //   rbuf@164,167,680 (41,746,432); stats@205,914,112 -> NEED_BIG = 205,924,352
  // SMALL: wvT@63,782,912; attn@70,598,656 (39,337,984);
  //   stats@109,936,640 -> NEED_SMALL = 109,946,880; rbuf@0 (aliases dead xbf)
  const size_t NEED_SMALL = 109946880;
  const size_t NEED_BIG   = 205924352;
  if (ws_size < NEED_SMALL) return;
  const bool big = (ws_size >= NEED_BIG);

  char* ws = (char*)d_ws;
  uint16_t* xbf   = (uint16_t*)(ws);
  uint16_t* kvxbf = (uint16_t*)(ws + 51380224);
  float*    kv    = (float*)(ws + 52183040);
  uint16_t* wqkT  = (uint16_t*)(ws + 55394304);
  uint16_t* a2    = (uint16_t*)(ws);             // big only
  uint16_t* attn;
  uint16_t* wvT;
  uint16_t* rbuf;
  float*    stats;
  if (big) {
    attn  = (uint16_t*)(ws + 118013952);
    wvT   = (uint16_t*)(ws + 157351936);
    rbuf  = (uint16_t*)(ws + 164167680);
    stats = (float*)(ws + 205914112);
  } else {
    wvT   = (uint16_t*)(ws + 63782912);
    attn  = (uint16_t*)(ws + 70598656);
    rbuf  = (uint16_t*)(ws);                     // aliases dead xbf
    stats = (float*)(ws + 109936640);
  }
  float* moms    = stats;           // 16*44 floats
  float* gn2sums = stats + 704;     // 16*6
  float* gn3sums = stats + 800;     // 16*2
  float* gn1ab   = stats + 1024;    // 48*16
  float* gn2ab   = stats + 1792;    // 48*16

  hipMemsetAsync(stats, 0, 4096, stream);
  k_kvx<<<1568, 256, 0, stream>>>(x, down_w, kvxbf, xbf);
  k_kv<<<dim3(16, 16), 256, 0, stream>>>(kvxbf, kv_w, kv);
  k_wqkv<<<dim3(16, 8, 2), 256, 0, stream>>>(kv, q_w, proj_w, wqkT, wvT);
  k_attn<<<dim3(49, 2, 16), 256, 0, stream>>>(xbf, wqkT, rel_b, attn);
  k_moms<<<dim3(49, 16), 256, 0, stream>>>(attn, moms);
  k_aff<<<1, 64, 0, stream>>>(moms, ew, gn1_s, gn1_b, gn1ab);
  if (big) {
    k_dla0_t<true><<<dim3(196, 16, 3), 256, 0, stream>>>(attn, ew, gn1ab, dw_w,
                                                         gn2sums, a2);
    k_aff2<<<1, 64, 0, stream>>>(gn2sums, gn2_s, gn2_b, gn2ab);
    k_dla1b<<<dim3(601, 16), 256, 0, stream>>>(a2, gn2ab, red_w, gn3sums, rbuf);
  } else {
    k_dla0_t<false><<<dim3(196, 16, 3), 256, 0, stream>>>(attn, ew, gn1ab, dw_w,
                                                          gn2sums, nullptr);
    k_aff2<<<1, 64, 0, stream>>>(gn2sums, gn2_s, gn2_b, gn2ab);
    k_dla1s<<<dim3(196, 16), 256, 0, stream>>>(attn, ew, gn1ab, dw_w, gn2ab,
                                               red_w, gn3sums, rbuf);
  }
  k_out<<<dim3(49, 4, 16), 256, 0, stream>>>(rbuf, wvT, gn3sums, gn3_s, gn3_b, proj_b, outp);
}

// Round 11
// 720.658 us; speedup vs baseline: 1.0921x; 1.0026x over previous
//
#include <hip/hip_runtime.h>
#include <hip/hip_bf16.h>
#include <stdint.h>

// Problem constants
#define B_    16
#define C_    512
#define HIMG  56
#define N_    3136
#define NK_   49
#define NH_   8
#define HD_   64
#define JP_   52          // padded NK (49 -> 52) so 8*52 = 416 = 13*32
#define J_    416
#define SST_  212         // Ss epilogue row stride (R7-proven)
#define HID_  24
#define POS_  153664      // N_ * NK_
#define PLH_  9834496     // u16 elems per attn head-plane: B_*N_*NK_*4
#define CNT_  1229312.0f  // 8 * 3136 * 49 (elements per group-norm group)
#define EPS_  1e-5f
#define SCALE_ 0.125f     // HEAD_DIM^-0.5

typedef __attribute__((ext_vector_type(8))) short short8;
typedef __attribute__((ext_vector_type(4))) float floatx4;

static __device__ __forceinline__ uint16_t f2bf(float f) {
  uint32_t u = __builtin_bit_cast(uint32_t, f);
  u = (u + 0x7FFFu + ((u >> 16) & 1u)) >> 16;
  return (uint16_t)u;
}
static __device__ __forceinline__ float bf2f(uint16_t h) {
  uint32_t u = ((uint32_t)h) << 16;
  return __builtin_bit_cast(float, u);
}
static __device__ __forceinline__ uint16_t f2h(float f) {
  _Float16 h = (_Float16)f;
  return __builtin_bit_cast(uint16_t, h);
}
static __device__ __forceinline__ float h2f(uint16_t u) {
  return (float)__builtin_bit_cast(_Float16, u);
}
static __device__ __forceinline__ float swishf(float z) {
  return z * __builtin_amdgcn_rcpf(1.f + __expf(-z));
}
// load 8 fp16 attn values for (b,n,m): 4 from each head-plane
static __device__ __forceinline__ void ld_attn8(const uint16_t* __restrict__ attn,
                                                size_t off, float* a) {
  uint2 v0 = *(const uint2*)(attn + off);
  uint2 v1 = *(const uint2*)(attn + PLH_ + off);
  a[0] = h2f((uint16_t)(v0.x & 0xFFFFu)); a[1] = h2f((uint16_t)(v0.x >> 16));
  a[2] = h2f((uint16_t)(v0.y & 0xFFFFu)); a[3] = h2f((uint16_t)(v0.y >> 16));
  a[4] = h2f((uint16_t)(v1.x & 0xFFFFu)); a[5] = h2f((uint16_t)(v1.x >> 16));
  a[6] = h2f((uint16_t)(v1.y & 0xFFFFu)); a[7] = h2f((uint16_t)(v1.y >> 16));
}

// gn1 affine (al,be) for group g's 8 channels from per-batch moments
static __device__ __forceinline__ void gn1_affine(const float* __restrict__ moms,
    const float* __restrict__ ew, const float* __restrict__ gs,
    const float* __restrict__ gb, int b, int g, float* al, float* be) {
  float m1[8];
#pragma unroll
  for (int h = 0; h < 8; ++h) m1[h] = moms[b * 44 + h];
  float sum = 0.f, ssq = 0.f;
#pragma unroll
  for (int o2 = 0; o2 < 8; ++o2) {
    int o = g * 8 + o2;
    float e[8];
#pragma unroll
    for (int h = 0; h < 8; ++h) e[h] = ew[o * 8 + h];
    float so = 0.f;
#pragma unroll
    for (int h = 0; h < 8; ++h) so += e[h] * m1[h];
    sum += so;
    int idx = 8;
#pragma unroll
    for (int h = 0; h < 8; ++h)
#pragma unroll
      for (int h2 = h; h2 < 8; ++h2) {
        float cf = e[h] * e[h2] * ((h == h2) ? 1.f : 2.f);
        ssq += cf * moms[b * 44 + idx];
        ++idx;
      }
  }
  float mean = sum * (1.f / CNT_);
  float var = ssq * (1.f / CNT_) - mean * mean;
  float inv = rsqrtf(var + EPS_);
#pragma unroll
  for (int o2 = 0; o2 < 8; ++o2) {
    al[o2] = inv * gs[g * 8 + o2];
    be[o2] = gb[g * 8 + o2] - mean * al[o2];
  }
}

// ---------------------------------------------------------------------------
// 1) kvxbf[b][m][c] (bf16) = depthwise 8x8/stride-8 downsample; also xbf
// ---------------------------------------------------------------------------
__global__ __launch_bounds__(256) void k_kvx(const float* __restrict__ x,
                                             const float* __restrict__ dw,
                                             uint16_t* __restrict__ kvxbf,
                                             uint16_t* __restrict__ xbf) {
  int g = blockIdx.x * 256 + threadIdx.x;
  int b = g / (C_ * NK_);
  int rem = g % (C_ * NK_);
  int c = rem / NK_;
  int m = rem % NK_;
  int ph = m / 7, pw = m % 7;
  const size_t base = ((size_t)(b * C_ + c)) * N_ + (ph * 8) * HIMG + pw * 8;
  const float* xp = x + base;
  uint16_t* xbp = xbf + base;
  const float* wp = dw + c * 64;
  float acc = 0.f;
#pragma unroll
  for (int i = 0; i < 8; ++i) {
    float4 a  = *(const float4*)(xp + i * HIMG);
    float4 bq = *(const float4*)(xp + i * HIMG + 4);
    acc += a.x*wp[i*8+0] + a.y*wp[i*8+1] + a.z*wp[i*8+2] + a.w*wp[i*8+3]
         + bq.x*wp[i*8+4] + bq.y*wp[i*8+5] + bq.z*wp[i*8+6] + bq.w*wp[i*8+7];
    uint32_t q0 = (uint32_t)f2bf(a.x)  | ((uint32_t)f2bf(a.y)  << 16);
    uint32_t q1 = (uint32_t)f2bf(a.z)  | ((uint32_t)f2bf(a.w)  << 16);
    uint32_t q2 = (uint32_t)f2bf(bq.x) | ((uint32_t)f2bf(bq.y) << 16);
    uint32_t q3 = (uint32_t)f2bf(bq.z) | ((uint32_t)f2bf(bq.w) << 16);
    *(uint4*)(xbp + (size_t)i * HIMG) = make_uint4(q0, q1, q2, q3);
  }
  kvxbf[((size_t)(b * NK_ + m)) * C_ + c] = f2bf(acc);
}

// ---------------------------------------------------------------------------
// 2) kv[b][m][col] = sum_c kvx[b][m][c] * kv_w[c][col]  -- MFMA bf16
// ---------------------------------------------------------------------------
__global__ __launch_bounds__(256) void k_kv(const uint16_t* __restrict__ kvxbf,
                                            const float* __restrict__ kv_w,
                                            float* __restrict__ kv) {
  const int ct = blockIdx.x, b = blockIdx.y;
  const int j0 = ct * 64;
  const int tid = threadIdx.x, wvid = tid >> 6, lane = tid & 63;
  __shared__ __align__(16) uint32_t A32[64 * 20];
  __shared__ __align__(16) uint32_t B32[64 * 20];
  floatx4 acc[4];
#pragma unroll
  for (int t = 0; t < 4; ++t) acc[t] = (floatx4){0.f,0.f,0.f,0.f};
  const int am = tid & 63, ak = tid >> 6;
  const int bj = tid & 63, bk = tid >> 6;
  for (int ks = 0; ks < 16; ++ks) {
    const int c0 = ks * 32;
    __syncthreads();
    {
      uint4 av = make_uint4(0, 0, 0, 0);
      if (am < NK_)
        av = *(const uint4*)(kvxbf + ((size_t)(b * NK_ + am)) * C_ + c0 + ak * 8);
      *(uint4*)&A32[am * 20 + ak * 4] = av;
    }
    {
      uint32_t pk[4];
#pragma unroll
      for (int r = 0; r < 4; ++r) {
        float f0 = kv_w[(size_t)(c0 + bk * 8 + 2 * r)     * 1024 + j0 + bj];
        float f1 = kv_w[(size_t)(c0 + bk * 8 + 2 * r + 1) * 1024 + j0 + bj];
        pk[r] = (uint32_t)f2bf(f0) | ((uint32_t)f2bf(f1) << 16);
      }
      *(uint4*)&B32[bj * 20 + bk * 4] = make_uint4(pk[0], pk[1], pk[2], pk[3]);
    }
    __syncthreads();
    short8 af = *(const short8*)&A32[(wvid * 16 + (lane & 15)) * 20 + (lane >> 4) * 4];
#pragma unroll
    for (int t = 0; t < 4; ++t) {
      short8 bfb = *(const short8*)&B32[(t * 16 + (lane & 15)) * 20 + (lane >> 4) * 4];
      acc[t] = __builtin_amdgcn_mfma_f32_16x16x32_bf16(af, bfb, acc[t], 0, 0, 0);
    }
  }
  const int rb = wvid * 16 + ((lane >> 4) << 2), cb = lane & 15;
#pragma unroll
  for (int t = 0; t < 4; ++t)
#pragma unroll
    for (int r2 = 0; r2 < 4; ++r2) {
      int m = rb + r2;
      if (m < NK_)
        kv[((size_t)(b * NK_ + m)) * 1024 + j0 + t * 16 + cb] = acc[t][r2];
    }
}

// ---------------------------------------------------------------------------
// 3+4 merged) z=0: wqkT[b][h*52+m][c] = SCALE*sum_d q_w[c][h*64+d]*k[b][h][m][d]
//             z=1: wvT[b][c'][h*52+m] = sum_d v[b][h][m][d]*proj_w[h*64+d][c']
// ---------------------------------------------------------------------------
__global__ __launch_bounds__(256) void k_wqkv(const float* __restrict__ kv,
                                              const float* __restrict__ q_w,
                                              const float* __restrict__ proj_w,
                                              uint16_t* __restrict__ wqkT,
                                              uint16_t* __restrict__ wvT) {
  int b = blockIdx.x, h = blockIdx.y;
  __shared__ float sm[56 * 64];
  if (blockIdx.z == 0) {
    for (int idx = threadIdx.x; idx < 56 * 64; idx += 256) {
      int m = idx >> 6, d = idx & 63;
      sm[idx] = (m < NK_) ? kv[((size_t)(b * NK_ + m)) * 1024 + h * HD_ + d] : 0.f;
    }
    __syncthreads();
#pragma unroll
    for (int cc = 0; cc < 2; ++cc) {
      int c = threadIdx.x + cc * 256;
      float qrow[64];
      const float* qp = q_w + (size_t)c * C_ + h * HD_;
#pragma unroll
      for (int d = 0; d < 64; ++d) qrow[d] = qp[d];
      for (int mc = 0; mc < NK_; mc += 8) {
        int cnt = min(8, NK_ - mc);
        float acc[8] = {0,0,0,0,0,0,0,0};
        for (int d = 0; d < 64; ++d) {
          float q = qrow[d];
#pragma unroll
          for (int i = 0; i < 8; ++i) acc[i] += q * sm[(mc + i) * 64 + d];
        }
        for (int i = 0; i < cnt; ++i)
          wqkT[((size_t)(b * J_ + h * JP_ + mc + i)) * C_ + c] = f2bf(acc[i] * SCALE_);
      }
    }
    for (int idx = threadIdx.x; idx < 3 * C_; idx += 256) {
      int rr = idx / C_, c = idx % C_;
      wqkT[((size_t)(b * J_ + h * JP_ + 49 + rr)) * C_ + c] = 0;
    }
  } else {
    for (int idx = threadIdx.x; idx < 56 * 64; idx += 256) {
      int m = idx >> 6, d = idx & 63;
      sm[idx] = (m < NK_) ? kv[((size_t)(b * NK_ + m)) * 1024 + 512 + h * HD_ + d] : 0.f;
    }
    __syncthreads();
#pragma unroll
    for (int cc = 0; cc < 2; ++cc) {
      int c = threadIdx.x + cc * 256;
      for (int mc = 0; mc < NK_; mc += 8) {
        int cnt = min(8, NK_ - mc);
        float acc[8] = {0,0,0,0,0,0,0,0};
        for (int d = 0; d < 64; ++d) {
          float w = proj_w[(size_t)(h * HD_ + d) * C_ + c];
#pragma unroll
          for (int i = 0; i < 8; ++i) acc[i] += sm[(mc + i) * 64 + d] * w;
        }
        uint16_t* dst = wvT + ((size_t)(b * C_ + c)) * J_ + h * JP_ + mc;
        if (cnt == 8) {
          uint32_t pk[4];
#pragma unroll
          for (int i = 0; i < 4; ++i)
            pk[i] = (uint32_t)f2bf(acc[2*i]) | ((uint32_t)f2bf(acc[2*i+1]) << 16);
          *(uint2*)(dst)     = make_uint2(pk[0], pk[1]);
          *(uint2*)(dst + 4) = make_uint2(pk[2], pk[3]);
        } else {
          for (int i = 0; i < cnt; ++i) dst[i] = f2bf(acc[i]);
        }
      }
      uint16_t* pd = wvT + ((size_t)(b * C_ + c)) * J_ + h * JP_ + 49;
      pd[0] = 0; pd[1] = 0; pd[2] = 0;
    }
  }
}

// ---------------------------------------------------------------------------
// 5) GEMM1 + softmax (R7 core). Flat grid (1568) with XCD-pairing swizzle:
//    a tile's two ct-halves get linear IDs 8 apart -> same XCD (round-robin)
//    and near-simultaneous dispatch -> partner's xbf reads hit L2/L3.
// ---------------------------------------------------------------------------
__global__ __launch_bounds__(256) void k_attn(const uint16_t* __restrict__ xbf,
                                              const uint16_t* __restrict__ wqkT,
                                              const float* __restrict__ rel_bias,
                                              uint16_t* __restrict__ attn) {
  // decode swizzled flat id: partners (ct=0/1 of same tile) are 8 apart
  const int fid = blockIdx.x;                 // 0..1567 (= 98*16)
  const int group = fid >> 4;                 // 0..97
  const int pair = fid & 7;                   // 0..7
  const int half = (fid >> 3) & 1;            // 0/1
  const int work = group * 16 + pair * 2 + half;
  const int b = work / 98;
  const int rem = work - b * 98;
  const int mt = rem >> 1, ct = rem & 1;
  const int n0 = mt * 64, j0 = ct * 208;
  const int tid = threadIdx.x, wvid = tid >> 6, lane = tid & 63;
  __shared__ __align__(16) char smem[64 * SST_ * 4];  // 54272 B
  uint32_t* A32 = (uint32_t*)smem;          // [64][20]
  uint32_t* B32 = A32 + 64 * 20;            // [208][20]
  float* Ss = (float*)smem;                 // [64][212] epilogue (aliases stage)

  floatx4 acc[13];
#pragma unroll
  for (int t = 0; t < 13; ++t) acc[t] = (floatx4){0.f,0.f,0.f,0.f};

  const int an = tid & 63, acp = tid >> 6;
  for (int ks = 0; ks < 16; ++ks) {
    const int c0 = ks * 32;
    __syncthreads();
    {
      const uint16_t* xb = xbf + ((size_t)(b * C_ + c0 + acp * 8)) * N_ + n0 + an;
      uint32_t pk[4];
#pragma unroll
      for (int jj = 0; jj < 4; ++jj) {
        uint32_t f0 = xb[(size_t)(2*jj) * N_];
        uint32_t f1 = xb[(size_t)(2*jj+1) * N_];
        pk[jj] = f0 | (f1 << 16);
      }
      *(uint4*)&A32[an * 20 + acp * 4] = make_uint4(pk[0], pk[1], pk[2], pk[3]);
    }
    for (int idx = tid; idx < 832; idx += 256) {
      int jl = idx >> 2, q = idx & 3;
      uint4 v = *(const uint4*)(wqkT + ((size_t)b * J_ + j0 + jl) * C_ + c0 + q * 8);
      *(uint4*)&B32[jl * 20 + q * 4] = v;
    }
    __syncthreads();
    short8 af = *(const short8*)&A32[(wvid * 16 + (lane & 15)) * 20 + (lane >> 4) * 4];
#pragma unroll
    for (int t = 0; t < 13; ++t) {
      short8 bfb = *(const short8*)&B32[(16 * t + (lane & 15)) * 20 + (lane >> 4) * 4];
      acc[t] = __builtin_amdgcn_mfma_f32_16x16x32_bf16(af, bfb, acc[t], 0, 0, 0);
    }
  }
  __syncthreads();
  {
    const int rb = wvid * 16 + ((lane >> 4) << 2), cb = lane & 15;
#pragma unroll
    for (int t = 0; t < 13; ++t)
#pragma unroll
      for (int r2 = 0; r2 < 4; ++r2)
        Ss[(rb + r2) * SST_ + t * 16 + cb] = acc[t][r2];
  }
  __syncthreads();
  {
    const int row = tid >> 2, hh = tid & 3;
    const int n = n0 + row;
    const float* bias = rel_bias + (size_t)n * NK_;
    float* srow = &Ss[row * SST_ + hh * JP_];
    float mx = -1e30f;
    for (int m = 0; m < NK_; ++m) mx = fmaxf(mx, srow[m] + bias[m]);
    float sum = 0.f;
    for (int m = 0; m < NK_; ++m) { float e = __expf(srow[m] + bias[m] - mx); srow[m] = e; sum += e; }
    float inv = 1.f / sum;
    for (int m = 0; m < NK_; ++m) srow[m] *= inv;
  }
  __syncthreads();
  // coalesced write: plane ct, [b][n][49][4] fp16
  uint16_t* dst = attn + (size_t)ct * PLH_ + ((size_t)b * N_ + n0) * NK_ * 4;
  for (int task = tid; task < 64 * NK_; task += 256) {
    int row = task / NK_, m = task % NK_;
    const float* sr = &Ss[row * SST_];
    uint32_t lo = (uint32_t)f2h(sr[m])         | ((uint32_t)f2h(sr[JP_ + m])   << 16);
    uint32_t hi = (uint32_t)f2h(sr[2*JP_ + m]) | ((uint32_t)f2h(sr[3*JP_ + m]) << 16);
    *(uint2*)(dst + (size_t)task * 4) = make_uint2(lo, hi);
  }
}

// ---------------------------------------------------------------------------
// 6) attn moments per batch (fp16 attn, two planes)
// ---------------------------------------------------------------------------
__global__ __launch_bounds__(256) void k_moms(const uint16_t* __restrict__ attn,
                                              float* __restrict__ moms) {
  int nt = blockIdx.x, b = blockIdx.y;
  float vals[44];
#pragma unroll
  for (int k = 0; k < 44; ++k) vals[k] = 0.f;
  for (int task = threadIdx.x; task < 64 * NK_; task += 256) {
    float a[8];
    ld_attn8(attn, ((size_t)b * N_ + nt * 64) * NK_ * 4 + (size_t)task * 4, a);
#pragma unroll
    for (int h = 0; h < 8; ++h) vals[h] += a[h];
    int idx = 8;
#pragma unroll
    for (int h = 0; h < 8; ++h)
#pragma unroll
      for (int h2 = h; h2 < 8; ++h2) { vals[idx] += a[h] * a[h2]; ++idx; }
  }
  __shared__ float red[4][44];
  int lane = threadIdx.x & 63, wvid = threadIdx.x >> 6;
#pragma unroll
  for (int k = 0; k < 44; ++k) {
#pragma unroll
    for (int off = 32; off; off >>= 1) vals[k] += __shfl_down(vals[k], off, 64);
  }
  if (lane == 0) {
#pragma unroll
    for (int k = 0; k < 44; ++k) red[wvid][k] = vals[k];
  }
  __syncthreads();
  if (threadIdx.x < 44) {
    float t = red[0][threadIdx.x] + red[1][threadIdx.x] + red[2][threadIdx.x] + red[3][threadIdx.x];
    atomicAdd(&moms[b * 44 + threadIdx.x], t);
  }
}

// ---------------------------------------------------------------------------
// 6b) gn1 affine precompute
// ---------------------------------------------------------------------------
__global__ void k_aff(const float* __restrict__ moms, const float* __restrict__ ew,
                      const float* __restrict__ gn1_s, const float* __restrict__ gn1_b,
                      float* __restrict__ gn1ab) {
  int t = threadIdx.x;
  if (t >= 48) return;
  int b = t / 3, g = t % 3;
  float al[8], be[8];
  gn1_affine(moms, ew, gn1_s, gn1_b, b, g, al, be);
#pragma unroll
  for (int o = 0; o < 8; ++o) { gn1ab[t * 16 + o] = al[o]; gn1ab[t * 16 + 8 + o] = be[o]; }
}

// ---------------------------------------------------------------------------
// 6c) gn2 affine precompute (after k_dla0)
// ---------------------------------------------------------------------------
__global__ void k_aff2(const float* __restrict__ gn2sums, const float* __restrict__ gn2_s,
                       const float* __restrict__ gn2_b, float* __restrict__ gn2ab) {
  int t = threadIdx.x;
  if (t >= 48) return;
  int b = t / 3, g = t % 3;
  float s2 = gn2sums[b * 6 + g * 2], q2 = gn2sums[b * 6 + g * 2 + 1];
  float mean = s2 * (1.f / CNT_);
  float var = q2 * (1.f / CNT_) - mean * mean;
  float inv = rsqrtf(var + EPS_);
#pragma unroll
  for (int o = 0; o < 8; ++o) {
    float al = inv * gn2_s[g * 8 + o];
    gn2ab[t * 16 + o] = al;
    gn2ab[t * 16 + 8 + o] = gn2_b[g * 8 + o] - mean * al;
  }
}

// ---------------------------------------------------------------------------
// 7a) DLA pass 0 (R7 per-group form): h1 -> LDS, 3x3 stencil -> a2;
//     gn2 sums; opt. store a2 fp16
// ---------------------------------------------------------------------------
template<bool STORE>
__global__ __launch_bounds__(256) void k_dla0_t(const uint16_t* __restrict__ attn,
    const float* __restrict__ ew, const float* __restrict__ gn1ab,
    const float* __restrict__ dww, float* __restrict__ gn2sums,
    uint16_t* __restrict__ a2buf) {
  const int nt = blockIdx.x, b = blockIdx.y, g = blockIdx.z;  // 196 x 16 x 3
  const int n0 = nt * 16;
  __shared__ __align__(16) float h1s[18 * 51 * 8];   // 29376 B
  __shared__ float red[4][2];
  float al[8], be[8];
  {
    const float* ab = gn1ab + (b * 3 + g) * 16;
#pragma unroll
    for (int o = 0; o < 8; ++o) { al[o] = ab[o]; be[o] = ab[8 + o]; }
  }
  for (int task = threadIdx.x; task < 18 * NK_; task += 256) {
    int r = task / NK_, m = task % NK_;
    int n = n0 - 1 + r;
    float h1v[8];
    if (n < 0 || n >= N_) {
#pragma unroll
      for (int o = 0; o < 8; ++o) h1v[o] = 0.f;
    } else {
      float a[8];
      ld_attn8(attn, (((size_t)b * N_ + n) * NK_ + m) * 4, a);
#pragma unroll
      for (int o = 0; o < 8; ++o) {
        float v = 0.f;
#pragma unroll
        for (int h = 0; h < 8; ++h) v += ew[(g * 8 + o) * 8 + h] * a[h];
        h1v[o] = swishf(v * al[o] + be[o]);
      }
    }
    float* dst = &h1s[(r * 51 + m + 1) * 8];
    *(float4*)dst = make_float4(h1v[0], h1v[1], h1v[2], h1v[3]);
    *(float4*)(dst + 4) = make_float4(h1v[4], h1v[5], h1v[6], h1v[7]);
  }
  for (int idx = threadIdx.x; idx < 18 * 16; idx += 256) {
    int r = idx >> 4, c = idx & 15;
    h1s[(r * 51 + (c >> 3) * 50) * 8 + (c & 7)] = 0.f;
  }
  __syncthreads();
  const int row = threadIdx.x >> 4, mg = threadIdx.x & 15;
  const int m0 = mg * 3;
  const int mlim = (mg == 15) ? 4 : 3;
  float a2[4][8];
#pragma unroll
  for (int mi = 0; mi < 4; ++mi)
#pragma unroll
    for (int o = 0; o < 8; ++o) a2[mi][o] = 0.f;
#pragma unroll
  for (int dr = 0; dr < 3; ++dr) {
    float win[48];
    const float* src = &h1s[((row + dr) * 51 + m0) * 8];
#pragma unroll
    for (int k = 0; k < 12; ++k)
      *(float4*)&win[k * 4] = *(const float4*)(src + k * 4);
#pragma unroll
    for (int o = 0; o < 8; ++o) {
      float wa = dww[(g * 8 + o) * 9 + dr * 3 + 0];
      float wb = dww[(g * 8 + o) * 9 + dr * 3 + 1];
      float wc = dww[(g * 8 + o) * 9 + dr * 3 + 2];
#pragma unroll
      for (int mi = 0; mi < 4; ++mi)
        a2[mi][o] += win[mi * 8 + o] * wa + win[(mi + 1) * 8 + o] * wb + win[(mi + 2) * 8 + o] * wc;
    }
  }
  float s0 = 0.f, q0 = 0.f;
#pragma unroll
  for (int mi = 0; mi < 4; ++mi) {
    if (mi < mlim) {
#pragma unroll
      for (int o = 0; o < 8; ++o) { s0 += a2[mi][o]; q0 += a2[mi][o] * a2[mi][o]; }
    }
  }
  int lane = threadIdx.x & 63, wvid = threadIdx.x >> 6;
#pragma unroll
  for (int off = 32; off; off >>= 1) { s0 += __shfl_down(s0, off, 64); q0 += __shfl_down(q0, off, 64); }
  if (lane == 0) { red[wvid][0] = s0; red[wvid][1] = q0; }
  __syncthreads();
  if (threadIdx.x < 2) {
    float t = red[0][threadIdx.x] + red[1][threadIdx.x] + red[2][threadIdx.x] + red[3][threadIdx.x];
    atomicAdd(&gn2sums[b * 6 + g * 2 + threadIdx.x], t);
  }
  if (STORE) {
    uint32_t* a2s = (uint32_t*)h1s;
#pragma unroll
    for (int mi = 0; mi < 4; ++mi) {
      if (mi < mlim) {
        uint32_t pk[4];
#pragma unroll
        for (int q = 0; q < 4; ++q)
          pk[q] = (uint32_t)f2h(a2[mi][2*q]) | ((uint32_t)f2h(a2[mi][2*q+1]) << 16);
        *(uint4*)&a2s[(row * NK_ + m0 + mi) * 4] = make_uint4(pk[0], pk[1], pk[2], pk[3]);
      }
    }
    __syncthreads();
    uint16_t* dstb = a2buf + ((size_t)(b * 3 + g) * POS_ + (size_t)n0 * NK_) * 8;
    for (int idx = threadIdx.x; idx < 16 * NK_; idx += 256)
      *(uint4*)(dstb + (size_t)idx * 8) = *(const uint4*)&a2s[idx * 4];
  }
}

// ---------------------------------------------------------------------------
// 7b-BIG) elementwise: a2 fp16 -> gn2 affine+swish -> 24->8 reduce -> rbuf
// ---------------------------------------------------------------------------
__global__ __launch_bounds__(256) void k_dla1b(const uint16_t* __restrict__ a2buf,
    const float* __restrict__ gn2ab, const float* __restrict__ rww,
    float* __restrict__ gn3sums, uint16_t* __restrict__ rbuf) {
  const int b = blockIdx.y;
  const int pos = blockIdx.x * 256 + threadIdx.x;
  __shared__ float rws[192];
  __shared__ float red[4][2];
  for (int i = threadIdx.x; i < 192; i += 256) rws[i] = rww[i];
  __syncthreads();
  float r[8] = {0.f,0.f,0.f,0.f,0.f,0.f,0.f,0.f};
  if (pos < POS_) {
#pragma unroll
    for (int g = 0; g < 3; ++g) {
      const float* ab = gn2ab + (b * 3 + g) * 16;
      uint4 v = *(const uint4*)(a2buf + ((size_t)(b * 3 + g) * POS_ + pos) * 8);
      uint32_t w[4] = {v.x, v.y, v.z, v.w};
#pragma unroll
      for (int q = 0; q < 4; ++q) {
#pragma unroll
        for (int hl = 0; hl < 2; ++hl) {
          int o = q * 2 + hl;
          float f = h2f((uint16_t)(hl ? (w[q] >> 16) : (w[q] & 0xFFFFu)));
          float sw = swishf(f * ab[o] + ab[8 + o]);
#pragma unroll
          for (int p = 0; p < 8; ++p) r[p] += rws[p * HID_ + g * 8 + o] * sw;
        }
      }
    }
  }
  float sr = 0.f, qr = 0.f;
#pragma unroll
  for (int p = 0; p < 8; ++p) { sr += r[p]; qr += r[p] * r[p]; }
  int lane = threadIdx.x & 63, wvid = threadIdx.x >> 6;
#pragma unroll
  for (int off = 32; off; off >>= 1) { sr += __shfl_down(sr, off, 64); qr += __shfl_down(qr, off, 64); }
  if (lane == 0) { red[wvid][0] = sr; red[wvid][1] = qr; }
  __syncthreads();
  if (threadIdx.x < 2) {
    float t = red[0][threadIdx.x] + red[1][threadIdx.x] + red[2][threadIdx.x] + red[3][threadIdx.x];
    atomicAdd(&gn3sums[b * 2 + threadIdx.x], t);
  }
  if (pos < POS_) {
    int n = pos / NK_, m = pos - n * NK_;
    uint16_t* dst = rbuf + ((size_t)b * N_ + n) * J_;
#pragma unroll
    for (int p = 0; p < 8; ++p) dst[p * JP_ + m] = f2bf(r[p]);
    if (m < 3) {
#pragma unroll
      for (int p = 0; p < 8; ++p) dst[p * JP_ + 49 + m] = 0;
    }
  }
}

// ---------------------------------------------------------------------------
// 7b-SMALL) fallback: recompute path (fp16 attn planes), precomputed affines
// ---------------------------------------------------------------------------
__global__ __launch_bounds__(256) void k_dla1s(const uint16_t* __restrict__ attn,
    const float* __restrict__ ew, const float* __restrict__ gn1ab,
    const float* __restrict__ dww, const float* __restrict__ gn2ab,
    const float* __restrict__ rww, float* __restrict__ gn3sums,
    uint16_t* __restrict__ rbuf) {
  const int nt = blockIdx.x, b = blockIdx.y;
  const int n0 = nt * 16;
  __shared__ __align__(16) float h1s[18 * 51 * 8];
  __shared__ float red[4][2];
  const int row = threadIdx.x >> 4, mg = threadIdx.x & 15;
  const int m0 = mg * 3;
  const int mlim = (mg == 15) ? 4 : 3;
  float racc[4][8];
#pragma unroll
  for (int mi = 0; mi < 4; ++mi)
#pragma unroll
    for (int p = 0; p < 8; ++p) racc[mi][p] = 0.f;

  for (int g = 0; g < 3; ++g) {
    float al[8], be[8], al2[8], be2[8];
    {
      const float* ab1 = gn1ab + (b * 3 + g) * 16;
      const float* ab2 = gn2ab + (b * 3 + g) * 16;
#pragma unroll
      for (int o = 0; o < 8; ++o) {
        al[o] = ab1[o]; be[o] = ab1[8 + o];
        al2[o] = ab2[o]; be2[o] = ab2[8 + o];
      }
    }
    __syncthreads();
    for (int task = threadIdx.x; task < 18 * NK_; task += 256) {
      int r = task / NK_, m = task % NK_;
      int n = n0 - 1 + r;
      float h1v[8];
      if (n < 0 || n >= N_) {
#pragma unroll
        for (int o = 0; o < 8; ++o) h1v[o] = 0.f;
      } else {
        float a[8];
        ld_attn8(attn, (((size_t)b * N_ + n) * NK_ + m) * 4, a);
#pragma unroll
        for (int o = 0; o < 8; ++o) {
          float v = 0.f;
#pragma unroll
          for (int h = 0; h < 8; ++h) v += ew[(g * 8 + o) * 8 + h] * a[h];
          h1v[o] = swishf(v * al[o] + be[o]);
        }
      }
      float* dst = &h1s[(r * 51 + m + 1) * 8];
      *(float4*)dst = make_float4(h1v[0], h1v[1], h1v[2], h1v[3]);
      *(float4*)(dst + 4) = make_float4(h1v[4], h1v[5], h1v[6], h1v[7]);
    }
    for (int idx = threadIdx.x; idx < 18 * 16; idx += 256) {
      int r = idx >> 4, c = idx & 15;
      h1s[(r * 51 + (c >> 3) * 50) * 8 + (c & 7)] = 0.f;
    }
    __syncthreads();
    float a2[4][8];
#pragma unroll
    for (int mi = 0; mi < 4; ++mi)
#pragma unroll
      for (int o = 0; o < 8; ++o) a2[mi][o] = 0.f;
#pragma unroll
    for (int dr = 0; dr < 3; ++dr) {
      float win[48];
      const float* src = &h1s[((row + dr) * 51 + m0) * 8];
#pragma unroll
      for (int k = 0; k < 12; ++k)
        *(float4*)&win[k * 4] = *(const float4*)(src + k * 4);
#pragma unroll
      for (int o = 0; o < 8; ++o) {
        float wa = dww[(g * 8 + o) * 9 + dr * 3 + 0];
        float wb = dww[(g * 8 + o) * 9 + dr * 3 + 1];
        float wc = dww[(g * 8 + o) * 9 + dr * 3 + 2];
#pragma unroll
        for (int mi = 0; mi < 4; ++mi)
          a2[mi][o] += win[mi * 8 + o] * wa + win[(mi + 1) * 8 + o] * wb + win[(mi + 2) * 8 + o] * wc;
      }
    }
#pragma unroll
    for (int mi = 0; mi < 4; ++mi) {
      if (mi < mlim) {
#pragma unroll
        for (int o = 0; o < 8; ++o) {
          float sw = swishf(a2[mi][o] * al2[o] + be2[o]);
#pragma unroll
          for (int p = 0; p < 8; ++p) racc[mi][p] += rww[p * HID_ + g * 8 + o] * sw;
        }
      }
    }
  }
  float sr = 0.f, qr = 0.f;
  const int n = n0 + row;
  uint16_t* dstbase = rbuf + ((size_t)b * N_ + n) * J_;
#pragma unroll
  for (int mi = 0; mi < 4; ++mi) {
    if (mi < mlim) {
      int m = m0 + mi;
#pragma unroll
      for (int p = 0; p < 8; ++p) {
        float v = racc[mi][p];
        dstbase[p * JP_ + m] = f2bf(v);
        sr += v; qr += v * v;
      }
    }
  }
  if (mg == 15) {
#pragma unroll
    for (int p = 0; p < 8; ++p) {
      dstbase[p * JP_ + 49] = 0; dstbase[p * JP_ + 50] = 0; dstbase[p * JP_ + 51] = 0;
    }
  }
  int lane = threadIdx.x & 63, wvid = threadIdx.x >> 6;
#pragma unroll
  for (int off = 32; off; off >>= 1) { sr += __shfl_down(sr, off, 64); qr += __shfl_down(qr, off, 64); }
  if (lane == 0) { red[wvid][0] = sr; red[wvid][1] = qr; }
  __syncthreads();
  if (threadIdx.x < 2) {
    float t = red[0][threadIdx.x] + red[1][threadIdx.x] + red[2][threadIdx.x] + red[3][threadIdx.x];
    atomicAdd(&gn3sums[b * 2 + threadIdx.x], t);
  }
}

// ---------------------------------------------------------------------------
// 8) GEMM2: out[b][n][c'] = sum_j gn3(r)[n][j] * wvT[b][c'][j] + proj_b[c']
// ---------------------------------------------------------------------------
__global__ __launch_bounds__(256) void k_out(const uint16_t* __restrict__ rr,
    const uint16_t* __restrict__ wvT, const float* __restrict__ gn3sums,
    const float* __restrict__ gn3_s, const float* __restrict__ gn3_b,
    const float* __restrict__ proj_b, float* __restrict__ outp) {
  const int mt = blockIdx.x, ct = blockIdx.y, b = blockIdx.z;
  const int n0 = mt * 64, c0 = ct * 128;
  const int tid = threadIdx.x, wvid = tid >> 6, lane = tid & 63;
  __shared__ __align__(16) uint32_t A32[64 * 20];
  __shared__ __align__(16) uint32_t B32[128 * 20];
  __shared__ float ab3[J_ * 2];
  {
    float ssum = gn3sums[b*2], sq = gn3sums[b*2+1];
    float mean = ssum * (1.f / CNT_);
    float var = sq * (1.f / CNT_) - mean * mean;
    float inv = rsqrtf(var + EPS_);
    for (int j = tid; j < J_; j += 256) {
      int h = j / JP_;
      float al = inv * gn3_s[h];
      ab3[j*2] = al; ab3[j*2+1] = gn3_b[h] - mean * al;
    }
  }
  floatx4 acc[8];
#pragma unroll
  for (int t = 0; t < 8; ++t) acc[t] = (floatx4){0.f,0.f,0.f,0.f};
  const int an = tid >> 2, acp = tid & 3;
  for (int ks = 0; ks < 13; ++ks) {
    const int k0 = ks * 32;
    __syncthreads();
    {
      const uint16_t* src = rr + ((size_t)b * N_ + n0 + an) * J_ + k0 + acp * 8;
      uint4 v = *(const uint4*)src;
      uint32_t raw[4] = {v.x, v.y, v.z, v.w};
      uint32_t pk[4];
#pragma unroll
      for (int jj = 0; jj < 4; ++jj) {
        int j = k0 + acp * 8 + jj * 2;
        float f0 = bf2f((uint16_t)(raw[jj] & 0xFFFFu)) * ab3[j*2]     + ab3[j*2+1];
        float f1 = bf2f((uint16_t)(raw[jj] >> 16))     * ab3[(j+1)*2] + ab3[(j+1)*2+1];
        pk[jj] = (uint32_t)f2bf(f0) | ((uint32_t)f2bf(f1) << 16);
      }
      *(uint4*)&A32[an * 20 + acp * 4] = make_uint4(pk[0], pk[1], pk[2], pk[3]);
    }
    for (int idx = tid; idx < 128 * 4; idx += 256) {
      int rw2 = idx >> 2, q = idx & 3;
      uint4 v = *(const uint4*)(wvT + ((size_t)b * C_ + c0 + rw2) * J_ + k0 + q * 8);
      *(uint4*)&B32[rw2 * 20 + q * 4] = v;
    }
    __syncthreads();
    short8 af = *(const short8*)&A32[(wvid * 16 + (lane & 15)) * 20 + (lane >> 4) * 4];
#pragma unroll
    for (int t = 0; t < 8; ++t) {
      short8 bfb = *(const short8*)&B32[(t * 16 + (lane & 15)) * 20 + (lane >> 4) * 4];
      acc[t] = __builtin_amdgcn_mfma_f32_16x16x32_bf16(af, bfb, acc[t], 0, 0, 0);
    }
  }
  const int rb = wvid * 16 + ((lane >> 4) << 2);
#pragma unroll
  for (int t = 0; t < 8; ++t) {
    int c = c0 + t * 16 + (lane & 15);
    float pb = proj_b[c];
#pragma unroll
    for (int r2 = 0; r2 < 4; ++r2)
      outp[((size_t)b * N_ + n0 + rb + r2) * C_ + c] = acc[t][r2] + pb;
  }
}

// ---------------------------------------------------------------------------
extern "C" void kernel_launch(void* const* d_in, const int* in_sizes, int n_in,
                              void* d_out, int out_size, void* d_ws, size_t ws_size,
                              hipStream_t stream) {
  (void)in_sizes; (void)n_in; (void)out_size;
  const float* x      = (const float*)d_in[0];
  const float* q_w    = (const float*)d_in[1];
  const float* down_w = (const float*)d_in[2];
  const float* kv_w   = (const float*)d_in[3];
  const float* proj_w = (const float*)d_in[4];
  const float* proj_b = (const float*)d_in[5];
  const float* rel_b  = (const float*)d_in[6];
  const float* ew     = (const float*)d_in[7];
  const float* gn1_s  = (const float*)d_in[8];
  const float* gn1_b  = (const float*)d_in[9];
  const float* dw_w   = (const float*)d_in[10];
  const float* gn2_s  = (const float*)d_in[11];
  const float* gn2_b  = (const float*)d_in[12];
  const float* red_w  = (const float*)d_in[13];
  const float* gn3_s  = (const float*)d_in[14];
  const float* gn3_b  = (const float*)d_in[15];
  float* outp = (float*)d_out;

  // Early region (both paths): xbf@0 (51,380,224); kvxbf@51,380,224 (802,816);
  //   kv@52,183,040 (3,211,264); wqkT@55,394,304 (8,388,608 slot) -> 63,782,912
  // BIG: a2@0 (118,013,952, overlaps dead early region);
  //   attn@118,013,952 (39,337,984 two planes); wvT@157,351,936 (6,815,744);
  //   rbuf@164,167,680 (41,746,432); stats@205,914,112 -> NEED_BIG = 205,924,352
  // SMALL: wvT@63,782,912; attn@70,598,656 (39,337,984);
  //   stats@109,936,640 -> NEED_SMALL = 109,946,880; rbuf@0 (aliases dead xbf)
  const size_t NEED_SMALL = 109946880;
  const size_t NEED_BIG   = 205924352;
  if (ws_size < NEED_SMALL) return;
  const bool big = (ws_size >= NEED_BIG);

  char* ws = (char*)d_ws;
  uint16_t* xbf   = (uint16_t*)(ws);
  uint16_t* kvxbf = (uint16_t*)(ws + 51380224);
  float*    kv    = (float*)(ws + 52183040);
  uint16_t* wqkT  = (uint16_t*)(ws + 55394304);
  uint16_t* a2    = (uint16_t*)(ws);             // big only
  uint16_t* attn;
  uint16_t* wvT;
  uint16_t* rbuf;
  float*    stats;
  if (big) {
    attn  = (uint16_t*)(ws + 118013952);
    wvT   = (uint16_t*)(ws + 157351936);
    rbuf  = (uint16_t*)(ws + 164167680);
    stats = (float*)(ws + 205914112);
  } else {
    wvT   = (uint16_t*)(ws + 63782912);
    attn  = (uint16_t*)(ws + 70598656);
    rbuf  = (uint16_t*)(ws);                     // aliases dead xbf
    stats = (float*)(ws + 109936640);
  }
  float* moms    = stats;           // 16*44 floats
  float* gn2sums = stats + 704;     // 16*6
  float* gn3sums = stats + 800;     // 16*2
  float* gn1ab   = stats + 1024;    // 48*16
  float* gn2ab   = stats + 1792;    // 48*16

  hipMemsetAsync(stats, 0, 4096, stream);
  k_kvx<<<1568, 256, 0, stream>>>(x, down_w, kvxbf, xbf);
  k_kv<<<dim3(16, 16), 256, 0, stream>>>(kvxbf, kv_w, kv);
  k_wqkv<<<dim3(16, 8, 2), 256, 0, stream>>>(kv, q_w, proj_w, wqkT, wvT);
  k_attn<<<dim3(1568), 256, 0, stream>>>(xbf, wqkT, rel_b, attn);
  k_moms<<<dim3(49, 16), 256, 0, stream>>>(attn, moms);
  k_aff<<<1, 64, 0, stream>>>(moms, ew, gn1_s, gn1_b, gn1ab);
  if (big) {
    k_dla0_t<true><<<dim3(196, 16, 3), 256, 0, stream>>>(attn, ew, gn1ab, dw_w,
                                                         gn2sums, a2);
    k_aff2<<<1, 64, 0, stream>>>(gn2sums, gn2_s, gn2_b, gn2ab);
    k_dla1b<<<dim3(601, 16), 256, 0, stream>>>(a2, gn2ab, red_w, gn3sums, rbuf);
  } else {
    k_dla0_t<false><<<dim3(196, 16, 3), 256, 0, stream>>>(attn, ew, gn1ab, dw_w,
                                                          gn2sums, nullptr);
    k_aff2<<<1, 64, 0, stream>>>(gn2sums, gn2_s, gn2_b, gn2ab);
    k_dla1s<<<dim3(196, 16), 256, 0, stream>>>(attn, ew, gn1ab, dw_w, gn2ab,
                                               red_w, gn3sums, rbuf);
  }
  k_out<<<dim3(49, 4, 16), 256, 0, stream>>>(rbuf, wvT, gn3sums, gn3_s, gn3_b, proj_b, outp);
}